// Round 11
// baseline (280.861 us; speedup 1.0000x reference)
//
#include <hip/hip_runtime.h>

#define B_ 4
#define C_ 256
#define N_ 4096
#define LOG2E 1.4426950408889634f

typedef short short8 __attribute__((ext_vector_type(8)));
typedef short short4_ __attribute__((ext_vector_type(4)));
typedef float float4v __attribute__((ext_vector_type(4)));
typedef unsigned int uint2v __attribute__((ext_vector_type(2)));
typedef unsigned int u32;

__device__ inline unsigned short f2b(float x){
  unsigned u = __builtin_bit_cast(unsigned, x);
  u = u + 0x7FFFu + ((u >> 16) & 1u);
  return (unsigned short)(u >> 16);
}

__device__ inline u32 cvtpk(float lo, float hi){
  u32 r; asm("v_cvt_pk_bf16_f32 %0, %1, %2" : "=v"(r) : "v"(lo), "v"(hi)); return r;
}

__device__ inline void gload16(const void* g, void* l){
  __builtin_amdgcn_global_load_lds((const __attribute__((address_space(1))) u32*)g,
                                   (__attribute__((address_space(3))) u32*)l, 16, 0, 0);
}

// ---------------- fold BN into weights (log2e folded into Q path) ----------------
__global__ void fold_w_kernel(const float* __restrict__ wq, const float* __restrict__ wk,
    const float* __restrict__ wv,
    const float* gq, const float* bq, const float* mq, const float* vq,
    const float* gk, const float* bk, const float* mk, const float* vk,
    const float* gv, const float* bv, const float* mv, const float* vv,
    unsigned short* wqb, unsigned short* wkb, unsigned short* wvb,
    float* biasq, float* biask, float* biasv){
  int i = blockIdx.x*256 + threadIdx.x;   // 65536 threads
  int o = i >> 8;
  float sv = gv[o]*rsqrtf(vv[o]+1e-5f);
  wvb[i] = f2b(wv[i]*sv);
  if (i < 32*256){
    int oq = i >> 8;
    float sq = gq[oq]*rsqrtf(vq[oq]+1e-5f);
    wqb[i] = f2b(wq[i]*sq*LOG2E);
    float sk = gk[oq]*rsqrtf(vk[oq]+1e-5f);
    wkb[i] = f2b(wk[i]*sk);
  }
  if (i < 256) biasv[i] = bv[i] - mv[i]*(gv[i]*rsqrtf(vv[i]+1e-5f));
  if (i < 32){
    biasq[i] = (bq[i] - mq[i]*(gq[i]*rsqrtf(vq[i]+1e-5f)))*LOG2E;
    biask[i] = bk[i] - mk[i]*(gk[i]*rsqrtf(vk[i]+1e-5f));
  }
}

// ------- preprocessing: z=0 (x<64) upsample+Qconv ; z=1 (128 blocks) x2 stage + K + full V -------
__global__ __launch_bounds__(256, 2)
void pre_kernel(const float* __restrict__ x1, const float* __restrict__ x2,
                const unsigned short* __restrict__ wqb,
                const unsigned short* __restrict__ wkb,
                const unsigned short* __restrict__ wvb,
                const float* __restrict__ biasq, const float* __restrict__ biask,
                const float* __restrict__ biasv,
                float* __restrict__ x1u,
                unsigned short* __restrict__ Qb, unsigned short* __restrict__ Kb,
                unsigned short* __restrict__ Vb){
  __shared__ unsigned short xt[64*260];
  int b = blockIdx.y;
  int t = threadIdx.x;
  int lane = t&63, w = t>>6, l15 = lane&15, g = lane>>4;

  if (blockIdx.z == 0){
    if (blockIdx.x >= 64) return;
    int y = blockIdx.x;
    float fy = 0.5f*y - 0.25f;
    float y0f = floorf(fy); float wy = fy - y0f;
    int y0 = max(0,min(31,(int)y0f)), y1 = max(0,min(31,(int)y0f+1));
    int x = t & 63, cg = t >> 6;
    float fx = 0.5f*x - 0.25f;
    float x0f = floorf(fx); float wx = fx - x0f;
    int x0 = max(0,min(31,(int)x0f)), x1i = max(0,min(31,(int)x0f+1));
    #pragma unroll 8
    for (int i=0;i<64;i++){
      int c = cg + i*4;
      const float* s0 = x1 + ((size_t)(b*C_ + c)*32 + y0)*32;
      const float* s1 = x1 + ((size_t)(b*C_ + c)*32 + y1)*32;
      float v00=s0[x0], v01=s0[x1i], v10=s1[x0], v11=s1[x1i];
      float v0 = v00 + wx*(v01-v00), v1 = v10 + wx*(v11-v10);
      float val = v0 + wy*(v1-v0);
      x1u[(size_t)(b*C_ + c)*N_ + y*64 + x] = val;
      xt[x*260 + c] = f2b(val);
    }
    __syncthreads();
    const unsigned short* arow = xt + (w*16+l15)*260 + g*8;
    short8 a[8];
    #pragma unroll
    for (int kk=0;kk<8;kk++){
      short4_ lo = *(const short4_*)(arow + kk*32);
      short4_ hi = *(const short4_*)(arow + kk*32 + 4);
      short8 af;
      af[0]=lo[0];af[1]=lo[1];af[2]=lo[2];af[3]=lo[3];
      af[4]=hi[0];af[5]=hi[1];af[6]=hi[2];af[7]=hi[3];
      a[kk]=af;
    }
    #pragma unroll
    for (int ot=0; ot<2; ot++){
      int o = ot*16 + l15;
      const unsigned short* wrow = wqb + o*C_ + g*8;
      float4v acc = {0.f,0.f,0.f,0.f};
      #pragma unroll
      for (int kk=0;kk<8;kk++){
        short8 bf = *(const short8*)(wrow + kk*32);
        acc = __builtin_amdgcn_mfma_f32_16x16x32_bf16(a[kk], bf, acc, 0,0,0);
      }
      float bs = biasq[o];
      #pragma unroll
      for (int r=0;r<4;r++){
        float yv = acc[r] + bs;
        yv = yv >= 0.f ? yv : 0.1f*yv;
        int m = y*64 + w*16 + g*4 + r;
        Qb[(size_t)(b*N_+m)*32 + o] = f2b(yv);
      }
    }
  } else {
    // 128 blocks of 32 n-cols; x2 read ONCE; K + all 16 V-rounds (half-size)
    int n0 = blockIdx.x*32;
    int n = t & 31, cg = t >> 5;   // 8 c-groups
    #pragma unroll 8
    for (int i=0;i<32;i++){
      int c = cg + i*8;
      float v = x2[(size_t)(b*C_ + c)*N_ + n0 + n];
      xt[n*260 + c] = f2b(v);
    }
    __syncthreads();
    int mt = w & 1;
    const unsigned short* arow = xt + (mt*16+l15)*260 + g*8;
    short8 a[8];
    #pragma unroll
    for (int kk=0;kk<8;kk++){
      short4_ lo = *(const short4_*)(arow + kk*32);
      short4_ hi = *(const short4_*)(arow + kk*32 + 4);
      short8 af;
      af[0]=lo[0];af[1]=lo[1];af[2]=lo[2];af[3]=lo[3];
      af[4]=hi[0];af[5]=hi[1];af[6]=hi[2];af[7]=hi[3];
      a[kk]=af;
    }
    if (w < 2){  // K conv: wave w -> m-tile w, o 0..31
      #pragma unroll
      for (int ot=0; ot<2; ot++){
        int o = ot*16 + l15;
        const unsigned short* wrow = wkb + o*C_ + g*8;
        float4v acc = {0.f,0.f,0.f,0.f};
        #pragma unroll
        for (int kk=0;kk<8;kk++){
          short8 bf = *(const short8*)(wrow + kk*32);
          acc = __builtin_amdgcn_mfma_f32_16x16x32_bf16(a[kk], bf, acc, 0,0,0);
        }
        float bs = biask[o];
        #pragma unroll
        for (int r=0;r<4;r++){
          float yv = acc[r] + bs;
          yv = yv >= 0.f ? yv : 0.1f*yv;
          int m = n0 + w*16 + g*4 + r;
          Kb[(size_t)(b*N_+m)*32 + o] = f2b(yv);
        }
      }
    }
    // V conv: wave w -> m-tile w&1, ot-range (w>>1)*8 .. +8
    #pragma unroll
    for (int i=0;i<8;i++){
      int o = ((w>>1)*8 + i)*16 + l15;
      const unsigned short* wrow = wvb + (size_t)o*C_ + g*8;
      float4v acc = {0.f,0.f,0.f,0.f};
      #pragma unroll
      for (int kk=0;kk<8;kk++){
        short8 bf = *(const short8*)(wrow + kk*32);
        acc = __builtin_amdgcn_mfma_f32_16x16x32_bf16(a[kk], bf, acc, 0,0,0);
      }
      float bs = biasv[o];
      #pragma unroll
      for (int r=0;r<4;r++){
        float yv = acc[r] + bs;
        yv = yv >= 0.f ? yv : 0.1f*yv;
        int m = n0 + mt*16 + g*4 + r;
        Vb[(size_t)(b*C_ + o)*N_ + m] = f2b(yv);
      }
    }
  }
}

// ---------------- fused flash attention + gamma*out + x1u ----------------
// Grid 256 (XCD-swizzled), 1024 threads = 16 waves = TWO independent 8-wave
// n-groups (ng = w>>3): group ng sweeps n in [ng*2048, ng*2048+2048), own V dbuf,
// own P buf, own softmax state. Within a group: wl = w&7; wl<4 softmax of 16-row
// tile wl; PV split cq=wl&3 (64 c), ks=wl>>2 (k-half). Epilogue merges the two
// groups' partials via (M,L) combine in LDS.
__global__ __launch_bounds__(1024, 2)
void attn_kernel(const unsigned short* __restrict__ Qb,
                 const unsigned short* __restrict__ Kb,
                 const unsigned short* __restrict__ Vb,
                 const float* __restrict__ x1u,
                 const float* __restrict__ gamma_p,
                 float* __restrict__ out){
  // [0,131072): V dbuf: ng*65536 + par*32768      | epilogue: cbuf[2 ng][4 cq][64 m][65] f32
  // [131072,147456): P: ng*8192 + mt*2048           (cbuf = [0,133120) overlays V + head of P)
  // 147456: flags[2 pp][2 ng][4 mt] int (64 B)
  // 147520: scl[2 pp][2 ng][64] f32 (2 KB)
  // 149568: stats[2 ng][64][2] f32 (1 KB)
  // 150592: facL[3][64] f32 (768 B)
  __shared__ __align__(16) char smem[151424];
  int* flagsB  = (int*)(smem + 147456);
  float* sclB  = (float*)(smem + 147520);
  float* stats = (float*)(smem + 149568);
  float* facL  = (float*)(smem + 150592);

  int wg = blockIdx.y*64 + blockIdx.x;
  int id = (wg & 7)*32 + (wg >> 3);           // bijective XCD swizzle (256 = 8*32)
  int b = id >> 6, mblk = id & 63;
  int t = threadIdx.x, lane = t & 63, w = t >> 6;
  int ng = w >> 3, wl = w & 7;
  int l15 = lane & 15, g = lane >> 4;
  int swz = (l15 & 7) << 4;
  int cq = wl & 3, ks = wl >> 2;

  short8 qf{};
  if (wl < 4)
    qf = *(const short8*)(Qb + (size_t)(b*N_ + mblk*64 + wl*16 + l15)*32 + g*8);

  float4v acc[4][4];   // [mt][ct] : 64 m x 64 c partial (k-half ks, group ng)
  #pragma unroll
  for (int mt=0;mt<4;mt++)
    #pragma unroll
    for (int ct=0;ct<4;ct++) acc[mt][ct] = (float4v){0.f,0.f,0.f,0.f};
  float mrow = -1e30f, lrun = 0.f;
  const float4v zero4 = {0.f,0.f,0.f,0.f};

  // V staging: per group, 2048 16B chunks over 512 threads -> 4 each
  u32 goff[4]; int loff[4];
  int lt = t & 511;
  #pragma unroll
  for (int j=0;j<4;j++){
    int i = j*512 + lt;
    int c = i >> 3, jj = i & 7;
    loff[j] = ng*65536 + i*16;
    goff[j] = (u32)(c*(N_*2)) + (u32)((jj ^ (c & 7)) << 4);
  }
  const char* Vbyte = (const char*)Vb + (size_t)b*C_*N_*2 + ng*4096;
  const short* kbase = (const short*)Kb + (size_t)(b*N_ + ng*2048 + l15)*32 + g*8;

  auto stageV = [&](int ttl, int par){
    const char* src = Vbyte + ttl*128;
    #pragma unroll
    for (int j=0;j<4;j++) gload16(src + goff[j], smem + loff[j] + par*32768);
  };
  auto loadK = [&](short8 (&kf)[4], int ttl){
    const short* kp = kbase + (size_t)ttl*64*32;
    #pragma unroll
    for (int j=0;j<4;j++) kf[j] = *(const short8*)(kp + j*512);
  };

  // phase A: QK + max/trig + exp2 + pack; leaves pk[] (4x uint2v) in regs
  auto softmaxA = [&](const short8 (&kf)[4], int pdst, uint2v (&pk)[4]){
    float4v s[4];
    #pragma unroll
    for (int j=0;j<4;j++)
      s[j] = __builtin_amdgcn_mfma_f32_16x16x32_bf16(kf[j], qf, zero4, 0, 0, 0);
    float tmax = fmaxf(fmaxf(fmaxf(s[0][0],s[0][1]),fmaxf(s[0][2],s[0][3])),
               fmaxf(fmaxf(fmaxf(s[1][0],s[1][1]),fmaxf(s[1][2],s[1][3])),
               fmaxf(fmaxf(fmaxf(s[2][0],s[2][1]),fmaxf(s[2][2],s[2][3])),
                     fmaxf(fmaxf(s[3][0],s[3][1]),fmaxf(s[3][2],s[3][3])))));
    int trig = __any((tmax > mrow + 8.f) ? 1 : 0) ? 1 : 0;
    if (lane == 0) flagsB[pdst*8 + ng*4 + wl] = trig;
    if (trig){
      float tm = fmaxf(tmax, __shfl_xor(tmax, 16));
      tm = fmaxf(tm, __shfl_xor(tm, 32));
      float mnew = fmaxf(mrow, tm);
      float sc = exp2f(mrow - mnew);
      mrow = mnew; lrun *= sc;
      if (lane < 16) sclB[(pdst*2 + ng)*64 + wl*16 + l15] = sc;
    }
    #pragma unroll
    for (int j=0;j<4;j++){
      float p0 = exp2f(s[j][0]-mrow), p1 = exp2f(s[j][1]-mrow);
      float p2 = exp2f(s[j][2]-mrow), p3 = exp2f(s[j][3]-mrow);
      lrun += (p0+p1)+(p2+p3);
      pk[j] = (uint2v){cvtpk(p0, p1), cvtpk(p2, p3)};
    }
  };
  // phase B: P write only (single buffer per group)
  auto softmaxB = [&](uint2v (&pk)[4]){
    char* pw = smem + 131072 + ng*8192 + wl*2048 + l15*128;
    #pragma unroll
    for (int j=0;j<4;j++)
      *(uint2v*)(pw + ((j*32 + g*8) ^ swz)) = pk[j];
  };

  auto body = [&](int tt, short8 (&kC)[4], short8 (&kN)[4], uint2v (&pk)[4]){
    int pp = tt & 1;
    // ---- phase A ----
    if (tt < 31) stageV(tt+1, (tt+1)&1);
    if (wl < 4){
      loadK(kN, (tt+2) & 31);
      if (tt < 31) softmaxA(kC, (tt+1)&1, pk);
    }
    // rescale partials with flags/scl of tile t (this group)
    #pragma unroll
    for (int mt=0;mt<4;mt++){
      if (flagsB[pp*8 + ng*4 + mt]){
        float4v sv = *(float4v*)(sclB + (pp*2+ng)*64 + mt*16 + g*4);
        #pragma unroll
        for (int ct=0;ct<4;ct++){
          acc[mt][ct][0]*=sv[0]; acc[mt][ct][1]*=sv[1];
          acc[mt][ct][2]*=sv[2]; acc[mt][ct][3]*=sv[3];
        }
      }
    }
    // PV(t): k-half ks, c-range cq*64, group ng
    int ko = (ks*64 + g*16) ^ swz;
    char* vbc = smem + ng*65536 + (tt&1)*32768;
    const char* pbase = smem + 131072 + ng*8192;
    short8 pa[4], vf[4];
    #pragma unroll
    for (int mt=0;mt<4;mt++)
      pa[mt] = *(const short8*)(pbase + mt*2048 + l15*128 + ko);
    #pragma unroll
    for (int ct=0;ct<4;ct++)
      vf[ct] = *(const short8*)(vbc + (cq*64 + ct*16 + l15)*128 + ko);
    __builtin_amdgcn_s_setprio(1);
    #pragma unroll
    for (int mt=0;mt<4;mt++)
      #pragma unroll
      for (int ct=0;ct<4;ct++)
        acc[mt][ct] = __builtin_amdgcn_mfma_f32_16x16x32_bf16(pa[mt], vf[ct], acc[mt][ct], 0, 0, 0);
    __builtin_amdgcn_s_setprio(0);
    __syncthreads();                 // barrier1: P readers done; stage(t+1) drained
    // ---- phase B ----
    if (wl < 4 && tt < 31) softmaxB(pk);
    __syncthreads();                 // barrier2: P(t+1) published
  };

  // prologue: stage V(0); full softmax(0) -> P buf, flags parity 0; kA = K(1)
  short8 kA[4], kB[4];
  uint2v pkA[4], pkB[4];
  stageV(0, 0);
  if (wl < 4){
    short8 k0[4];
    loadK(k0, 0);
    softmaxA(k0, 0, pkA);
    softmaxB(pkA);
    loadK(kA, 1);
  }
  __syncthreads();

  for (int tt=0; tt<32; tt+=2){
    body(tt,   kA, kB, pkA);
    body(tt+1, kB, kA, pkB);
  }

  // ---------- epilogue: per-group l-reduce, cross-group (M,L) merge, store ----------
  if (wl < 4){
    lrun += __shfl_xor(lrun, 16);
    lrun += __shfl_xor(lrun, 32);
    if (lane < 16){
      stats[(ng*64 + wl*16 + l15)*2    ] = mrow;
      stats[(ng*64 + wl*16 + l15)*2 + 1] = lrun;
    }
  }
  float* cbg = (float*)smem + ng*16640 + cq*4160;   // [64 m][65] f32 per (ng,cq)
  if (ks == 1){
    #pragma unroll
    for (int mt=0;mt<4;mt++)
      #pragma unroll
      for (int ct=0;ct<4;ct++)
        #pragma unroll
        for (int r=0;r<4;r++)
          cbg[(mt*16 + g*4 + r)*65 + ct*16 + l15] = acc[mt][ct][r];
  }
  __syncthreads();
  if (t < 64){
    float m0s = stats[t*2],        l0 = stats[t*2 + 1];
    float m1s = stats[(64+t)*2],   l1 = stats[(64+t)*2 + 1];
    float M = fmaxf(m0s, m1s);
    float f0 = exp2f(m0s - M), f1 = exp2f(m1s - M);
    float L = l0*f0 + l1*f1;
    facL[t] = f0; facL[64+t] = f1; facL[128+t] = 1.f/L;
  }
  if (ks == 0){
    #pragma unroll
    for (int mt=0;mt<4;mt++)
      #pragma unroll
      for (int ct=0;ct<4;ct++)
        #pragma unroll
        for (int r=0;r<4;r++)
          cbg[(mt*16 + g*4 + r)*65 + ct*16 + l15] += acc[mt][ct][r];
  }
  __syncthreads();
  float gm = gamma_p[0];
  const float* cb0 = (float*)smem + cq*4160;
  const float* cb1 = cb0 + 16640;
  float fw0 = facL[lane]*facL[128+lane]*gm;
  float fw1 = facL[64+lane]*facL[128+lane]*gm;
  const float* xr = x1u + (size_t)(b*C_ + cq*64)*N_ + mblk*64;
  float* orow = out + (size_t)(b*C_ + cq*64)*N_ + mblk*64;
  #pragma unroll 8
  for (int i=0; i<16; i++){
    int c_l = ks*32 + ng*16 + i;
    float v = cb0[lane*65 + c_l]*fw0 + cb1[lane*65 + c_l]*fw1;
    orow[(size_t)c_l*N_ + lane] = v + xr[(size_t)c_l*N_ + lane];
  }
}

extern "C" void kernel_launch(void* const* d_in, const int* in_sizes, int n_in,
                              void* d_out, int out_size, void* d_ws, size_t ws_size,
                              hipStream_t stream){
  (void)in_sizes; (void)n_in; (void)out_size; (void)ws_size;
  const float* x1 = (const float*)d_in[0];
  const float* x2 = (const float*)d_in[1];
  const float* wq = (const float*)d_in[2];
  const float* wk = (const float*)d_in[3];
  const float* wv = (const float*)d_in[4];
  const float* gq = (const float*)d_in[5];
  const float* bq = (const float*)d_in[6];
  const float* mq = (const float*)d_in[7];
  const float* vq = (const float*)d_in[8];
  const float* gk = (const float*)d_in[9];
  const float* bk = (const float*)d_in[10];
  const float* mk = (const float*)d_in[11];
  const float* vk = (const float*)d_in[12];
  const float* gv = (const float*)d_in[13];
  const float* bv = (const float*)d_in[14];
  const float* mv = (const float*)d_in[15];
  const float* vv = (const float*)d_in[16];
  const float* gamma = (const float*)d_in[17];
  float* out = (float*)d_out;

  char* p = (char*)d_ws;
  float* x1u          = (float*)p;          p += (size_t)B_*C_*N_*4;   // 16 MB
  unsigned short* Qb  = (unsigned short*)p; p += (size_t)B_*N_*32*2;   // 1 MB
  unsigned short* Kb  = (unsigned short*)p; p += (size_t)B_*N_*32*2;   // 1 MB
  unsigned short* Vb  = (unsigned short*)p; p += (size_t)B_*C_*N_*2;   // 8 MB
  unsigned short* wqb = (unsigned short*)p; p += 32*256*2;
  unsigned short* wkb = (unsigned short*)p; p += 32*256*2;
  unsigned short* wvb = (unsigned short*)p; p += 256*256*2;
  float* biasq        = (float*)p;          p += 32*4;
  float* biask        = (float*)p;          p += 32*4;
  float* biasv        = (float*)p;          p += 256*4;

  fold_w_kernel<<<256, 256, 0, stream>>>(wq,wk,wv,gq,bq,mq,vq,gk,bk,mk,vk,gv,bv,mv,vv,
                                         wqb,wkb,wvb,biasq,biask,biasv);
  pre_kernel<<<dim3(128,4,2), 256, 0, stream>>>(x1, x2, wqb, wkb, wvb,
                                                biasq, biask, biasv, x1u, Qb, Kb, Vb);
  attn_kernel<<<dim3(64,4), 1024, 0, stream>>>(Qb, Kb, Vb, x1u, gamma, out);
}

// Round 12
// 279.973 us; speedup vs baseline: 1.0032x; 1.0032x over previous
//
#include <hip/hip_runtime.h>

#define B_ 4
#define C_ 256
#define N_ 4096
#define LOG2E 1.4426950408889634f

typedef short short8 __attribute__((ext_vector_type(8)));
typedef short short4_ __attribute__((ext_vector_type(4)));
typedef float float4v __attribute__((ext_vector_type(4)));
typedef unsigned int uint2v __attribute__((ext_vector_type(2)));
typedef unsigned int u32;

__device__ inline unsigned short f2b(float x){
  unsigned u = __builtin_bit_cast(unsigned, x);
  u = u + 0x7FFFu + ((u >> 16) & 1u);
  return (unsigned short)(u >> 16);
}

__device__ inline u32 cvtpk(float lo, float hi){
  u32 r; asm("v_cvt_pk_bf16_f32 %0, %1, %2" : "=v"(r) : "v"(lo), "v"(hi)); return r;
}

__device__ inline void gload16(const void* g, void* l){
  __builtin_amdgcn_global_load_lds((const __attribute__((address_space(1))) u32*)g,
                                   (__attribute__((address_space(3))) u32*)l, 16, 0, 0);
}

// ---------------- fold BN into weights (log2e folded into Q path) ----------------
__global__ void fold_w_kernel(const float* __restrict__ wq, const float* __restrict__ wk,
    const float* __restrict__ wv,
    const float* gq, const float* bq, const float* mq, const float* vq,
    const float* gk, const float* bk, const float* mk, const float* vk,
    const float* gv, const float* bv, const float* mv, const float* vv,
    unsigned short* wqb, unsigned short* wkb, unsigned short* wvb,
    float* biasq, float* biask, float* biasv){
  int i = blockIdx.x*256 + threadIdx.x;   // 65536 threads
  int o = i >> 8;
  float sv = gv[o]*rsqrtf(vv[o]+1e-5f);
  wvb[i] = f2b(wv[i]*sv);
  if (i < 32*256){
    int oq = i >> 8;
    float sq = gq[oq]*rsqrtf(vq[oq]+1e-5f);
    wqb[i] = f2b(wq[i]*sq*LOG2E);
    float sk = gk[oq]*rsqrtf(vk[oq]+1e-5f);
    wkb[i] = f2b(wk[i]*sk);
  }
  if (i < 256) biasv[i] = bv[i] - mv[i]*(gv[i]*rsqrtf(vv[i]+1e-5f));
  if (i < 32){
    biasq[i] = (bq[i] - mq[i]*(gq[i]*rsqrtf(vq[i]+1e-5f)))*LOG2E;
    biask[i] = bk[i] - mk[i]*(gk[i]*rsqrtf(vk[i]+1e-5f));
  }
}

// ------- preprocessing: z=0 (x<64) upsample+Qconv ; z=1 (128 blocks) x2 stage + K + full V -------
__global__ __launch_bounds__(256, 2)
void pre_kernel(const float* __restrict__ x1, const float* __restrict__ x2,
                const unsigned short* __restrict__ wqb,
                const unsigned short* __restrict__ wkb,
                const unsigned short* __restrict__ wvb,
                const float* __restrict__ biasq, const float* __restrict__ biask,
                const float* __restrict__ biasv,
                float* __restrict__ x1u,
                unsigned short* __restrict__ Qb, unsigned short* __restrict__ Kb,
                unsigned short* __restrict__ Vb){
  __shared__ unsigned short xt[64*260];
  int b = blockIdx.y;
  int t = threadIdx.x;
  int lane = t&63, w = t>>6, l15 = lane&15, g = lane>>4;

  if (blockIdx.z == 0){
    if (blockIdx.x >= 64) return;
    int y = blockIdx.x;
    float fy = 0.5f*y - 0.25f;
    float y0f = floorf(fy); float wy = fy - y0f;
    int y0 = max(0,min(31,(int)y0f)), y1 = max(0,min(31,(int)y0f+1));
    int x = t & 63, cg = t >> 6;
    float fx = 0.5f*x - 0.25f;
    float x0f = floorf(fx); float wx = fx - x0f;
    int x0 = max(0,min(31,(int)x0f)), x1i = max(0,min(31,(int)x0f+1));
    #pragma unroll 8
    for (int i=0;i<64;i++){
      int c = cg + i*4;
      const float* s0 = x1 + ((size_t)(b*C_ + c)*32 + y0)*32;
      const float* s1 = x1 + ((size_t)(b*C_ + c)*32 + y1)*32;
      float v00=s0[x0], v01=s0[x1i], v10=s1[x0], v11=s1[x1i];
      float v0 = v00 + wx*(v01-v00), v1 = v10 + wx*(v11-v10);
      float val = v0 + wy*(v1-v0);
      x1u[(size_t)(b*C_ + c)*N_ + y*64 + x] = val;
      xt[x*260 + c] = f2b(val);
    }
    __syncthreads();
    const unsigned short* arow = xt + (w*16+l15)*260 + g*8;
    short8 a[8];
    #pragma unroll
    for (int kk=0;kk<8;kk++){
      short4_ lo = *(const short4_*)(arow + kk*32);
      short4_ hi = *(const short4_*)(arow + kk*32 + 4);
      short8 af;
      af[0]=lo[0];af[1]=lo[1];af[2]=lo[2];af[3]=lo[3];
      af[4]=hi[0];af[5]=hi[1];af[6]=hi[2];af[7]=hi[3];
      a[kk]=af;
    }
    #pragma unroll
    for (int ot=0; ot<2; ot++){
      int o = ot*16 + l15;
      const unsigned short* wrow = wqb + o*C_ + g*8;
      float4v acc = {0.f,0.f,0.f,0.f};
      #pragma unroll
      for (int kk=0;kk<8;kk++){
        short8 bf = *(const short8*)(wrow + kk*32);
        acc = __builtin_amdgcn_mfma_f32_16x16x32_bf16(a[kk], bf, acc, 0,0,0);
      }
      float bs = biasq[o];
      #pragma unroll
      for (int r=0;r<4;r++){
        float yv = acc[r] + bs;
        yv = yv >= 0.f ? yv : 0.1f*yv;
        int m = y*64 + w*16 + g*4 + r;
        Qb[(size_t)(b*N_+m)*32 + o] = f2b(yv);
      }
    }
  } else {
    // 128 blocks of 32 n-cols; x2 read ONCE; K + all 16 V-rounds (half-size)
    int n0 = blockIdx.x*32;
    int n = t & 31, cg = t >> 5;   // 8 c-groups
    #pragma unroll 8
    for (int i=0;i<32;i++){
      int c = cg + i*8;
      float v = x2[(size_t)(b*C_ + c)*N_ + n0 + n];
      xt[n*260 + c] = f2b(v);
    }
    __syncthreads();
    int mt = w & 1;
    const unsigned short* arow = xt + (mt*16+l15)*260 + g*8;
    short8 a[8];
    #pragma unroll
    for (int kk=0;kk<8;kk++){
      short4_ lo = *(const short4_*)(arow + kk*32);
      short4_ hi = *(const short4_*)(arow + kk*32 + 4);
      short8 af;
      af[0]=lo[0];af[1]=lo[1];af[2]=lo[2];af[3]=lo[3];
      af[4]=hi[0];af[5]=hi[1];af[6]=hi[2];af[7]=hi[3];
      a[kk]=af;
    }
    if (w < 2){  // K conv: wave w -> m-tile w, o 0..31
      #pragma unroll
      for (int ot=0; ot<2; ot++){
        int o = ot*16 + l15;
        const unsigned short* wrow = wkb + o*C_ + g*8;
        float4v acc = {0.f,0.f,0.f,0.f};
        #pragma unroll
        for (int kk=0;kk<8;kk++){
          short8 bf = *(const short8*)(wrow + kk*32);
          acc = __builtin_amdgcn_mfma_f32_16x16x32_bf16(a[kk], bf, acc, 0,0,0);
        }
        float bs = biask[o];
        #pragma unroll
        for (int r=0;r<4;r++){
          float yv = acc[r] + bs;
          yv = yv >= 0.f ? yv : 0.1f*yv;
          int m = n0 + w*16 + g*4 + r;
          Kb[(size_t)(b*N_+m)*32 + o] = f2b(yv);
        }
      }
    }
    // V conv: wave w -> m-tile w&1, ot-range (w>>1)*8 .. +8
    #pragma unroll
    for (int i=0;i<8;i++){
      int o = ((w>>1)*8 + i)*16 + l15;
      const unsigned short* wrow = wvb + (size_t)o*C_ + g*8;
      float4v acc = {0.f,0.f,0.f,0.f};
      #pragma unroll
      for (int kk=0;kk<8;kk++){
        short8 bf = *(const short8*)(wrow + kk*32);
        acc = __builtin_amdgcn_mfma_f32_16x16x32_bf16(a[kk], bf, acc, 0,0,0);
      }
      float bs = biasv[o];
      #pragma unroll
      for (int r=0;r<4;r++){
        float yv = acc[r] + bs;
        yv = yv >= 0.f ? yv : 0.1f*yv;
        int m = n0 + mt*16 + g*4 + r;
        Vb[(size_t)(b*C_ + o)*N_ + m] = f2b(yv);
      }
    }
  }
}

// ---------------- fused flash attention + gamma*out + x1u ----------------
// Grid 256 (XCD-swizzled), 1024 threads = 16 waves = TWO independent 8-wave
// n-groups (ng = w>>3). ONE block per CU by design; launch_bounds(1024,1):
// hipcc's 2nd arg acts like CUDA min-blocks-per-CU -- (1024,2) capped VGPR at 64
// and spilled the accumulators (R11: 406 MB scratch writes). (1024,1) -> cap 128.
__global__ __launch_bounds__(1024, 1)
void attn_kernel(const unsigned short* __restrict__ Qb,
                 const unsigned short* __restrict__ Kb,
                 const unsigned short* __restrict__ Vb,
                 const float* __restrict__ x1u,
                 const float* __restrict__ gamma_p,
                 float* __restrict__ out){
  // [0,131072): V dbuf: ng*65536 + par*32768      | epilogue: cbuf[2 ng][4 cq][64 m][65] f32
  // [131072,147456): P: ng*8192 + mt*2048           (cbuf = [0,133120) overlays V + head of P)
  // 147456: flags[2 pp][2 ng][4 mt] int (64 B)
  // 147520: scl[2 pp][2 ng][64] f32 (2 KB)
  // 149568: stats[2 ng][64][2] f32 (1 KB)
  // 150592: facL[3][64] f32 (768 B)
  __shared__ __align__(16) char smem[151424];
  int* flagsB  = (int*)(smem + 147456);
  float* sclB  = (float*)(smem + 147520);
  float* stats = (float*)(smem + 149568);
  float* facL  = (float*)(smem + 150592);

  int wg = blockIdx.y*64 + blockIdx.x;
  int id = (wg & 7)*32 + (wg >> 3);           // bijective XCD swizzle (256 = 8*32)
  int b = id >> 6, mblk = id & 63;
  int t = threadIdx.x, lane = t & 63, w = t >> 6;
  int ng = w >> 3, wl = w & 7;
  int l15 = lane & 15, g = lane >> 4;
  int swz = (l15 & 7) << 4;
  int cq = wl & 3, ks = wl >> 2;

  short8 qf{};
  if (wl < 4)
    qf = *(const short8*)(Qb + (size_t)(b*N_ + mblk*64 + wl*16 + l15)*32 + g*8);

  float4v acc[4][4];   // [mt][ct] : 64 m x 64 c partial (k-half ks, group ng)
  #pragma unroll
  for (int mt=0;mt<4;mt++)
    #pragma unroll
    for (int ct=0;ct<4;ct++) acc[mt][ct] = (float4v){0.f,0.f,0.f,0.f};
  float mrow = -1e30f, lrun = 0.f;
  const float4v zero4 = {0.f,0.f,0.f,0.f};

  // V staging: per group, 2048 16B chunks over 512 threads -> 4 each
  u32 goff[4]; int loff[4];
  int lt = t & 511;
  #pragma unroll
  for (int j=0;j<4;j++){
    int i = j*512 + lt;
    int c = i >> 3, jj = i & 7;
    loff[j] = ng*65536 + i*16;
    goff[j] = (u32)(c*(N_*2)) + (u32)((jj ^ (c & 7)) << 4);
  }
  const char* Vbyte = (const char*)Vb + (size_t)b*C_*N_*2 + ng*4096;
  const short* kbase = (const short*)Kb + (size_t)(b*N_ + ng*2048 + l15)*32 + g*8;

  auto stageV = [&](int ttl, int par){
    const char* src = Vbyte + ttl*128;
    #pragma unroll
    for (int j=0;j<4;j++) gload16(src + goff[j], smem + loff[j] + par*32768);
  };
  auto loadK = [&](short8 (&kf)[4], int ttl){
    const short* kp = kbase + (size_t)ttl*64*32;
    #pragma unroll
    for (int j=0;j<4;j++) kf[j] = *(const short8*)(kp + j*512);
  };

  // phase A: QK + max/trig + exp2 + pack; leaves pk[] (4x uint2v) in regs
  auto softmaxA = [&](const short8 (&kf)[4], int pdst, uint2v (&pk)[4]){
    float4v s[4];
    #pragma unroll
    for (int j=0;j<4;j++)
      s[j] = __builtin_amdgcn_mfma_f32_16x16x32_bf16(kf[j], qf, zero4, 0, 0, 0);
    float tmax = fmaxf(fmaxf(fmaxf(s[0][0],s[0][1]),fmaxf(s[0][2],s[0][3])),
               fmaxf(fmaxf(fmaxf(s[1][0],s[1][1]),fmaxf(s[1][2],s[1][3])),
               fmaxf(fmaxf(fmaxf(s[2][0],s[2][1]),fmaxf(s[2][2],s[2][3])),
                     fmaxf(fmaxf(s[3][0],s[3][1]),fmaxf(s[3][2],s[3][3])))));
    int trig = __any((tmax > mrow + 8.f) ? 1 : 0) ? 1 : 0;
    if (lane == 0) flagsB[pdst*8 + ng*4 + wl] = trig;
    if (trig){
      float tm = fmaxf(tmax, __shfl_xor(tmax, 16));
      tm = fmaxf(tm, __shfl_xor(tm, 32));
      float mnew = fmaxf(mrow, tm);
      float sc = exp2f(mrow - mnew);
      mrow = mnew; lrun *= sc;
      if (lane < 16) sclB[(pdst*2 + ng)*64 + wl*16 + l15] = sc;
    }
    #pragma unroll
    for (int j=0;j<4;j++){
      float p0 = exp2f(s[j][0]-mrow), p1 = exp2f(s[j][1]-mrow);
      float p2 = exp2f(s[j][2]-mrow), p3 = exp2f(s[j][3]-mrow);
      lrun += (p0+p1)+(p2+p3);
      pk[j] = (uint2v){cvtpk(p0, p1), cvtpk(p2, p3)};
    }
  };
  // phase B: P write only (single buffer per group)
  auto softmaxB = [&](uint2v (&pk)[4]){
    char* pw = smem + 131072 + ng*8192 + wl*2048 + l15*128;
    #pragma unroll
    for (int j=0;j<4;j++)
      *(uint2v*)(pw + ((j*32 + g*8) ^ swz)) = pk[j];
  };

  auto body = [&](int tt, short8 (&kC)[4], short8 (&kN)[4], uint2v (&pk)[4]){
    int pp = tt & 1;
    // ---- phase A ----
    if (tt < 31) stageV(tt+1, (tt+1)&1);
    if (wl < 4){
      loadK(kN, (tt+2) & 31);
      if (tt < 31) softmaxA(kC, (tt+1)&1, pk);
    }
    // rescale partials with flags/scl of tile t (this group)
    #pragma unroll
    for (int mt=0;mt<4;mt++){
      if (flagsB[pp*8 + ng*4 + mt]){
        float4v sv = *(float4v*)(sclB + (pp*2+ng)*64 + mt*16 + g*4);
        #pragma unroll
        for (int ct=0;ct<4;ct++){
          acc[mt][ct][0]*=sv[0]; acc[mt][ct][1]*=sv[1];
          acc[mt][ct][2]*=sv[2]; acc[mt][ct][3]*=sv[3];
        }
      }
    }
    // PV(t): k-half ks, c-range cq*64, group ng
    int ko = (ks*64 + g*16) ^ swz;
    char* vbc = smem + ng*65536 + (tt&1)*32768;
    const char* pbase = smem + 131072 + ng*8192;
    short8 pa[4], vf[4];
    #pragma unroll
    for (int mt=0;mt<4;mt++)
      pa[mt] = *(const short8*)(pbase + mt*2048 + l15*128 + ko);
    #pragma unroll
    for (int ct=0;ct<4;ct++)
      vf[ct] = *(const short8*)(vbc + (cq*64 + ct*16 + l15)*128 + ko);
    __builtin_amdgcn_s_setprio(1);
    #pragma unroll
    for (int mt=0;mt<4;mt++)
      #pragma unroll
      for (int ct=0;ct<4;ct++)
        acc[mt][ct] = __builtin_amdgcn_mfma_f32_16x16x32_bf16(pa[mt], vf[ct], acc[mt][ct], 0, 0, 0);
    __builtin_amdgcn_s_setprio(0);
    __syncthreads();                 // barrier1: P readers done; stage(t+1) drained
    // ---- phase B ----
    if (wl < 4 && tt < 31) softmaxB(pk);
    __syncthreads();                 // barrier2: P(t+1) published
  };

  // prologue: stage V(0); full softmax(0) -> P buf, flags parity 0; kA = K(1)
  short8 kA[4], kB[4];
  uint2v pkA[4], pkB[4];
  stageV(0, 0);
  if (wl < 4){
    short8 k0[4];
    loadK(k0, 0);
    softmaxA(k0, 0, pkA);
    softmaxB(pkA);
    loadK(kA, 1);
  }
  __syncthreads();

  for (int tt=0; tt<32; tt+=2){
    body(tt,   kA, kB, pkA);
    body(tt+1, kB, kA, pkB);
  }

  // ---------- epilogue: per-group l-reduce, cross-group (M,L) merge, store ----------
  if (wl < 4){
    lrun += __shfl_xor(lrun, 16);
    lrun += __shfl_xor(lrun, 32);
    if (lane < 16){
      stats[(ng*64 + wl*16 + l15)*2    ] = mrow;
      stats[(ng*64 + wl*16 + l15)*2 + 1] = lrun;
    }
  }
  float* cbg = (float*)smem + ng*16640 + cq*4160;   // [64 m][65] f32 per (ng,cq)
  if (ks == 1){
    #pragma unroll
    for (int mt=0;mt<4;mt++)
      #pragma unroll
      for (int ct=0;ct<4;ct++)
        #pragma unroll
        for (int r=0;r<4;r++)
          cbg[(mt*16 + g*4 + r)*65 + ct*16 + l15] = acc[mt][ct][r];
  }
  __syncthreads();
  if (t < 64){
    float m0s = stats[t*2],        l0 = stats[t*2 + 1];
    float m1s = stats[(64+t)*2],   l1 = stats[(64+t)*2 + 1];
    float M = fmaxf(m0s, m1s);
    float f0 = exp2f(m0s - M), f1 = exp2f(m1s - M);
    float L = l0*f0 + l1*f1;
    facL[t] = f0; facL[64+t] = f1; facL[128+t] = 1.f/L;
  }
  if (ks == 0){
    #pragma unroll
    for (int mt=0;mt<4;mt++)
      #pragma unroll
      for (int ct=0;ct<4;ct++)
        #pragma unroll
        for (int r=0;r<4;r++)
          cbg[(mt*16 + g*4 + r)*65 + ct*16 + l15] += acc[mt][ct][r];
  }
  __syncthreads();
  float gm = gamma_p[0];
  const float* cb0 = (float*)smem + cq*4160;
  const float* cb1 = cb0 + 16640;
  float fw0 = facL[lane]*facL[128+lane]*gm;
  float fw1 = facL[64+lane]*facL[128+lane]*gm;
  const float* xr = x1u + (size_t)(b*C_ + cq*64)*N_ + mblk*64;
  float* orow = out + (size_t)(b*C_ + cq*64)*N_ + mblk*64;
  #pragma unroll 8
  for (int i=0; i<16; i++){
    int c_l = ks*32 + ng*16 + i;
    float v = cb0[lane*65 + c_l]*fw0 + cb1[lane*65 + c_l]*fw1;
    orow[(size_t)c_l*N_ + lane] = v + xr[(size_t)c_l*N_ + lane];
  }
}

extern "C" void kernel_launch(void* const* d_in, const int* in_sizes, int n_in,
                              void* d_out, int out_size, void* d_ws, size_t ws_size,
                              hipStream_t stream){
  (void)in_sizes; (void)n_in; (void)out_size; (void)ws_size;
  const float* x1 = (const float*)d_in[0];
  const float* x2 = (const float*)d_in[1];
  const float* wq = (const float*)d_in[2];
  const float* wk = (const float*)d_in[3];
  const float* wv = (const float*)d_in[4];
  const float* gq = (const float*)d_in[5];
  const float* bq = (const float*)d_in[6];
  const float* mq = (const float*)d_in[7];
  const float* vq = (const float*)d_in[8];
  const float* gk = (const float*)d_in[9];
  const float* bk = (const float*)d_in[10];
  const float* mk = (const float*)d_in[11];
  const float* vk = (const float*)d_in[12];
  const float* gv = (const float*)d_in[13];
  const float* bv = (const float*)d_in[14];
  const float* mv = (const float*)d_in[15];
  const float* vv = (const float*)d_in[16];
  const float* gamma = (const float*)d_in[17];
  float* out = (float*)d_out;

  char* p = (char*)d_ws;
  float* x1u          = (float*)p;          p += (size_t)B_*C_*N_*4;   // 16 MB
  unsigned short* Qb  = (unsigned short*)p; p += (size_t)B_*N_*32*2;   // 1 MB
  unsigned short* Kb  = (unsigned short*)p; p += (size_t)B_*N_*32*2;   // 1 MB
  unsigned short* Vb  = (unsigned short*)p; p += (size_t)B_*C_*N_*2;   // 8 MB
  unsigned short* wqb = (unsigned short*)p; p += 32*256*2;
  unsigned short* wkb = (unsigned short*)p; p += 32*256*2;
  unsigned short* wvb = (unsigned short*)p; p += 256*256*2;
  float* biasq        = (float*)p;          p += 32*4;
  float* biask        = (float*)p;          p += 32*4;
  float* biasv        = (float*)p;          p += 256*4;

  fold_w_kernel<<<256, 256, 0, stream>>>(wq,wk,wv,gq,bq,mq,vq,gk,bk,mk,vk,gv,bv,mv,vv,
                                         wqb,wkb,wvb,biasq,biask,biasv);
  pre_kernel<<<dim3(128,4,2), 256, 0, stream>>>(x1, x2, wqb, wkb, wvb,
                                                biasq, biask, biasv, x1u, Qb, Kb, Vb);
  attn_kernel<<<dim3(64,4), 1024, 0, stream>>>(Qb, Kb, Vb, x1u, gamma, out);
}

// Round 13
// 165.760 us; speedup vs baseline: 1.6944x; 1.6890x over previous
//
#include <hip/hip_runtime.h>

#define B_ 4
#define C_ 256
#define N_ 4096
#define LOG2E 1.4426950408889634f

typedef short short8 __attribute__((ext_vector_type(8)));
typedef short short4_ __attribute__((ext_vector_type(4)));
typedef float float4v __attribute__((ext_vector_type(4)));
typedef unsigned int uint2v __attribute__((ext_vector_type(2)));
typedef unsigned int u32;

__device__ inline unsigned short f2b(float x){
  unsigned u = __builtin_bit_cast(unsigned, x);
  u = u + 0x7FFFu + ((u >> 16) & 1u);
  return (unsigned short)(u >> 16);
}

__device__ inline u32 cvtpk(float lo, float hi){
  u32 r; asm("v_cvt_pk_bf16_f32 %0, %1, %2" : "=v"(r) : "v"(lo), "v"(hi)); return r;
}

__device__ inline void gload16(const void* g, void* l){
  __builtin_amdgcn_global_load_lds((const __attribute__((address_space(1))) u32*)g,
                                   (__attribute__((address_space(3))) u32*)l, 16, 0, 0);
}

// ---------------- fold BN into weights (log2e folded into Q path) ----------------
__global__ void fold_w_kernel(const float* __restrict__ wq, const float* __restrict__ wk,
    const float* __restrict__ wv,
    const float* gq, const float* bq, const float* mq, const float* vq,
    const float* gk, const float* bk, const float* mk, const float* vk,
    const float* gv, const float* bv, const float* mv, const float* vv,
    unsigned short* wqb, unsigned short* wkb, unsigned short* wvb,
    float* biasq, float* biask, float* biasv){
  int i = blockIdx.x*256 + threadIdx.x;   // 65536 threads
  int o = i >> 8;
  float sv = gv[o]*rsqrtf(vv[o]+1e-5f);
  wvb[i] = f2b(wv[i]*sv);
  if (i < 32*256){
    int oq = i >> 8;
    float sq = gq[oq]*rsqrtf(vq[oq]+1e-5f);
    wqb[i] = f2b(wq[i]*sq*LOG2E);
    float sk = gk[oq]*rsqrtf(vk[oq]+1e-5f);
    wkb[i] = f2b(wk[i]*sk);
  }
  if (i < 256) biasv[i] = bv[i] - mv[i]*(gv[i]*rsqrtf(vv[i]+1e-5f));
  if (i < 32){
    biasq[i] = (bq[i] - mq[i]*(gq[i]*rsqrtf(vq[i]+1e-5f)))*LOG2E;
    biask[i] = bk[i] - mk[i]*(gk[i]*rsqrtf(vk[i]+1e-5f));
  }
}

// ------- preprocessing: z=0 (x<64) upsample+Qconv ; z=1 (128 blocks) x2 stage + K + full V -------
__global__ __launch_bounds__(256, 2)
void pre_kernel(const float* __restrict__ x1, const float* __restrict__ x2,
                const unsigned short* __restrict__ wqb,
                const unsigned short* __restrict__ wkb,
                const unsigned short* __restrict__ wvb,
                const float* __restrict__ biasq, const float* __restrict__ biask,
                const float* __restrict__ biasv,
                float* __restrict__ x1u,
                unsigned short* __restrict__ Qb, unsigned short* __restrict__ Kb,
                unsigned short* __restrict__ Vb){
  __shared__ unsigned short xt[64*260];
  int b = blockIdx.y;
  int t = threadIdx.x;
  int lane = t&63, w = t>>6, l15 = lane&15, g = lane>>4;

  if (blockIdx.z == 0){
    if (blockIdx.x >= 64) return;
    int y = blockIdx.x;
    float fy = 0.5f*y - 0.25f;
    float y0f = floorf(fy); float wy = fy - y0f;
    int y0 = max(0,min(31,(int)y0f)), y1 = max(0,min(31,(int)y0f+1));
    int x = t & 63, cg = t >> 6;
    float fx = 0.5f*x - 0.25f;
    float x0f = floorf(fx); float wx = fx - x0f;
    int x0 = max(0,min(31,(int)x0f)), x1i = max(0,min(31,(int)x0f+1));
    #pragma unroll 8
    for (int i=0;i<64;i++){
      int c = cg + i*4;
      const float* s0 = x1 + ((size_t)(b*C_ + c)*32 + y0)*32;
      const float* s1 = x1 + ((size_t)(b*C_ + c)*32 + y1)*32;
      float v00=s0[x0], v01=s0[x1i], v10=s1[x0], v11=s1[x1i];
      float v0 = v00 + wx*(v01-v00), v1 = v10 + wx*(v11-v10);
      float val = v0 + wy*(v1-v0);
      x1u[(size_t)(b*C_ + c)*N_ + y*64 + x] = val;
      xt[x*260 + c] = f2b(val);
    }
    __syncthreads();
    const unsigned short* arow = xt + (w*16+l15)*260 + g*8;
    short8 a[8];
    #pragma unroll
    for (int kk=0;kk<8;kk++){
      short4_ lo = *(const short4_*)(arow + kk*32);
      short4_ hi = *(const short4_*)(arow + kk*32 + 4);
      short8 af;
      af[0]=lo[0];af[1]=lo[1];af[2]=lo[2];af[3]=lo[3];
      af[4]=hi[0];af[5]=hi[1];af[6]=hi[2];af[7]=hi[3];
      a[kk]=af;
    }
    #pragma unroll
    for (int ot=0; ot<2; ot++){
      int o = ot*16 + l15;
      const unsigned short* wrow = wqb + o*C_ + g*8;
      float4v acc = {0.f,0.f,0.f,0.f};
      #pragma unroll
      for (int kk=0;kk<8;kk++){
        short8 bf = *(const short8*)(wrow + kk*32);
        acc = __builtin_amdgcn_mfma_f32_16x16x32_bf16(a[kk], bf, acc, 0,0,0);
      }
      float bs = biasq[o];
      #pragma unroll
      for (int r=0;r<4;r++){
        float yv = acc[r] + bs;
        yv = yv >= 0.f ? yv : 0.1f*yv;
        int m = y*64 + w*16 + g*4 + r;
        Qb[(size_t)(b*N_+m)*32 + o] = f2b(yv);
      }
    }
  } else {
    // 128 blocks of 32 n-cols; x2 read ONCE; K + all 16 V-rounds (half-size)
    int n0 = blockIdx.x*32;
    int n = t & 31, cg = t >> 5;   // 8 c-groups
    #pragma unroll 8
    for (int i=0;i<32;i++){
      int c = cg + i*8;
      float v = x2[(size_t)(b*C_ + c)*N_ + n0 + n];
      xt[n*260 + c] = f2b(v);
    }
    __syncthreads();
    int mt = w & 1;
    const unsigned short* arow = xt + (mt*16+l15)*260 + g*8;
    short8 a[8];
    #pragma unroll
    for (int kk=0;kk<8;kk++){
      short4_ lo = *(const short4_*)(arow + kk*32);
      short4_ hi = *(const short4_*)(arow + kk*32 + 4);
      short8 af;
      af[0]=lo[0];af[1]=lo[1];af[2]=lo[2];af[3]=lo[3];
      af[4]=hi[0];af[5]=hi[1];af[6]=hi[2];af[7]=hi[3];
      a[kk]=af;
    }
    if (w < 2){  // K conv: wave w -> m-tile w, o 0..31
      #pragma unroll
      for (int ot=0; ot<2; ot++){
        int o = ot*16 + l15;
        const unsigned short* wrow = wkb + o*C_ + g*8;
        float4v acc = {0.f,0.f,0.f,0.f};
        #pragma unroll
        for (int kk=0;kk<8;kk++){
          short8 bf = *(const short8*)(wrow + kk*32);
          acc = __builtin_amdgcn_mfma_f32_16x16x32_bf16(a[kk], bf, acc, 0,0,0);
        }
        float bs = biask[o];
        #pragma unroll
        for (int r=0;r<4;r++){
          float yv = acc[r] + bs;
          yv = yv >= 0.f ? yv : 0.1f*yv;
          int m = n0 + w*16 + g*4 + r;
          Kb[(size_t)(b*N_+m)*32 + o] = f2b(yv);
        }
      }
    }
    // V conv: wave w -> m-tile w&1, ot-range (w>>1)*8 .. +8
    #pragma unroll
    for (int i=0;i<8;i++){
      int o = ((w>>1)*8 + i)*16 + l15;
      const unsigned short* wrow = wvb + (size_t)o*C_ + g*8;
      float4v acc = {0.f,0.f,0.f,0.f};
      #pragma unroll
      for (int kk=0;kk<8;kk++){
        short8 bf = *(const short8*)(wrow + kk*32);
        acc = __builtin_amdgcn_mfma_f32_16x16x32_bf16(a[kk], bf, acc, 0,0,0);
      }
      float bs = biasv[o];
      #pragma unroll
      for (int r=0;r<4;r++){
        float yv = acc[r] + bs;
        yv = yv >= 0.f ? yv : 0.1f*yv;
        int m = n0 + mt*16 + g*4 + r;
        Vb[(size_t)(b*C_ + o)*N_ + m] = f2b(yv);
      }
    }
  }
}

// ---------------- fused flash attention + gamma*out + x1u ----------------
// Grid 512 (XCD-swizzled: 128 m-blocks of 32 rows x 4 b), 512 threads (8 waves),
// 2 blocks/CU (LDS ~70KB, VGPR ~100 under (512,2) -- the proven-safe shape;
// 1024-thread blocks force VGPR<=64 and spill (R8/R11/R12)).
// Waves 0,1: softmax of 16-row tile w. All 8 waves: PV split cq=w&3 (64 c),
// ks=w>>2 (k-half 32). Single P buffer + 2-barrier phases; defer-max; V LDS dbuf.
__global__ __launch_bounds__(512, 2)
void attn_kernel(const unsigned short* __restrict__ Qb,
                 const unsigned short* __restrict__ Kb,
                 const unsigned short* __restrict__ Vb,
                 const float* __restrict__ x1u,
                 const float* __restrict__ gamma_p,
                 float* __restrict__ out){
  // [0,65536): V dbuf (2x32768) | epilogue cbuf[4 cq][32 m][65] f32 overlays [0,33280)
  // [65536,69632): P (2 tiles x 2048)
  // 69632: flags[2 pp][2 mt] int ; 69648: scl[2 pp][32] f32 ; 69904: lst[32] f32
  __shared__ __align__(16) char smem[70032];
  int* flagsB = (int*)(smem + 69632);
  float* sclB = (float*)(smem + 69648);
  float* lst  = (float*)(smem + 69904);

  int wg = blockIdx.y*128 + blockIdx.x;
  int id = (wg & 7)*64 + (wg >> 3);           // bijective XCD swizzle (512 = 8*64)
  int b = id >> 7, mblk = id & 127;
  int t = threadIdx.x, lane = t & 63, w = t >> 6;
  int l15 = lane & 15, g = lane >> 4;
  int swz = (l15 & 7) << 4;
  int cq = w & 3, ks = w >> 2;

  short8 qf{};
  if (w < 2)
    qf = *(const short8*)(Qb + (size_t)(b*N_ + mblk*32 + w*16 + l15)*32 + g*8);

  float4v acc[2][4];   // [mt][ct] : 32 m x 64 c partial (k-half ks)
  #pragma unroll
  for (int mt=0;mt<2;mt++)
    #pragma unroll
    for (int ct=0;ct<4;ct++) acc[mt][ct] = (float4v){0.f,0.f,0.f,0.f};
  float mrow = -1e30f, lrun = 0.f;
  const float4v zero4 = {0.f,0.f,0.f,0.f};

  // V staging: 2048 16B chunks over 512 threads -> 4 each (linear LDS, inv-swz src)
  u32 goff[4]; int loff[4];
  #pragma unroll
  for (int j=0;j<4;j++){
    int i = j*512 + t;
    int c = i >> 3, jj = i & 7;
    loff[j] = i*16;
    goff[j] = (u32)(c*(N_*2)) + (u32)((jj ^ (c & 7)) << 4);
  }
  const char* Vbyte = (const char*)Vb + (size_t)b*C_*N_*2;
  const short* kbase = (const short*)Kb + (size_t)(b*N_ + l15)*32 + g*8;

  auto stageV = [&](int tt, int par){
    const char* src = Vbyte + tt*128;
    #pragma unroll
    for (int j=0;j<4;j++) gload16(src + goff[j], smem + loff[j] + par*32768);
  };
  auto loadK = [&](short8 (&kf)[4], int tt){
    const short* kp = kbase + (size_t)tt*64*32;
    #pragma unroll
    for (int j=0;j<4;j++) kf[j] = *(const short8*)(kp + j*512);
  };

  // phase A: QK + max/trig + exp2 + pack; leaves pk[] (4x uint2v) in regs
  auto softmaxA = [&](const short8 (&kf)[4], int pdst, uint2v (&pk)[4]){
    float4v s[4];
    #pragma unroll
    for (int j=0;j<4;j++)
      s[j] = __builtin_amdgcn_mfma_f32_16x16x32_bf16(kf[j], qf, zero4, 0, 0, 0);
    float tmax = fmaxf(fmaxf(fmaxf(s[0][0],s[0][1]),fmaxf(s[0][2],s[0][3])),
               fmaxf(fmaxf(fmaxf(s[1][0],s[1][1]),fmaxf(s[1][2],s[1][3])),
               fmaxf(fmaxf(fmaxf(s[2][0],s[2][1]),fmaxf(s[2][2],s[2][3])),
                     fmaxf(fmaxf(s[3][0],s[3][1]),fmaxf(s[3][2],s[3][3])))));
    int trig = __any((tmax > mrow + 8.f) ? 1 : 0) ? 1 : 0;
    if (lane == 0) flagsB[pdst*2 + w] = trig;
    if (trig){
      float tm = fmaxf(tmax, __shfl_xor(tmax, 16));
      tm = fmaxf(tm, __shfl_xor(tm, 32));
      float mnew = fmaxf(mrow, tm);
      float sc = exp2f(mrow - mnew);
      mrow = mnew; lrun *= sc;
      if (lane < 16) sclB[pdst*32 + w*16 + l15] = sc;
    }
    #pragma unroll
    for (int j=0;j<4;j++){
      float p0 = exp2f(s[j][0]-mrow), p1 = exp2f(s[j][1]-mrow);
      float p2 = exp2f(s[j][2]-mrow), p3 = exp2f(s[j][3]-mrow);
      lrun += (p0+p1)+(p2+p3);
      pk[j] = (uint2v){cvtpk(p0, p1), cvtpk(p2, p3)};
    }
  };
  // phase B: P write only (single buffer)
  auto softmaxB = [&](uint2v (&pk)[4]){
    char* pw = smem + 65536 + w*2048 + l15*128;
    #pragma unroll
    for (int j=0;j<4;j++)
      *(uint2v*)(pw + ((j*32 + g*8) ^ swz)) = pk[j];
  };

  auto body = [&](int tt, short8 (&kC)[4], short8 (&kN)[4], uint2v (&pk)[4]){
    int pp = tt & 1;
    // ---- phase A ----
    if (tt < 63) stageV(tt+1, (tt+1)&1);
    if (w < 2){
      loadK(kN, (tt+2) & 63);
      if (tt < 63) softmaxA(kC, (tt+1)&1, pk);
    }
    // rescale partials with flags/scl of tile t
    #pragma unroll
    for (int mt=0;mt<2;mt++){
      if (flagsB[pp*2 + mt]){
        float4v sv = *(float4v*)(sclB + pp*32 + mt*16 + g*4);
        #pragma unroll
        for (int ct=0;ct<4;ct++){
          acc[mt][ct][0]*=sv[0]; acc[mt][ct][1]*=sv[1];
          acc[mt][ct][2]*=sv[2]; acc[mt][ct][3]*=sv[3];
        }
      }
    }
    // PV(t): k-half ks, c-range cq*64
    int ko = (ks*64 + g*16) ^ swz;
    char* vbc = smem + (tt&1)*32768;
    const char* pbase = smem + 65536;
    short8 pa[2], vf[4];
    #pragma unroll
    for (int mt=0;mt<2;mt++)
      pa[mt] = *(const short8*)(pbase + mt*2048 + l15*128 + ko);
    #pragma unroll
    for (int ct=0;ct<4;ct++)
      vf[ct] = *(const short8*)(vbc + (cq*64 + ct*16 + l15)*128 + ko);
    __builtin_amdgcn_s_setprio(1);
    #pragma unroll
    for (int mt=0;mt<2;mt++)
      #pragma unroll
      for (int ct=0;ct<4;ct++)
        acc[mt][ct] = __builtin_amdgcn_mfma_f32_16x16x32_bf16(pa[mt], vf[ct], acc[mt][ct], 0, 0, 0);
    __builtin_amdgcn_s_setprio(0);
    __syncthreads();                 // barrier1: P readers done; stage(t+1) drained
    // ---- phase B ----
    if (w < 2 && tt < 63) softmaxB(pk);
    __syncthreads();                 // barrier2: P(t+1) published
  };

  // prologue: stage V(0); full softmax(0) -> P buf, flags parity 0; kA = K(1)
  short8 kA[4], kB[4];
  uint2v pkA[4], pkB[4];
  stageV(0, 0);
  if (w < 2){
    short8 k0[4];
    loadK(k0, 0);
    softmaxA(k0, 0, pkA);
    softmaxB(pkA);
    loadK(kA, 1);
  }
  __syncthreads();

  for (int tt=0; tt<64; tt+=2){
    body(tt,   kA, kB, pkA);
    body(tt+1, kB, kA, pkB);
  }

  // ---------- epilogue: l-reduce, k-partial combine, normalize, store ----------
  if (w < 2){
    lrun += __shfl_xor(lrun, 16);
    lrun += __shfl_xor(lrun, 32);
    if (lane < 16) lst[w*16 + l15] = lrun;
  }
  float* cb = (float*)smem + cq*2080;   // [32 m][65] f32 per cq (overlays V)
  if (ks == 1){
    #pragma unroll
    for (int mt=0;mt<2;mt++)
      #pragma unroll
      for (int ct=0;ct<4;ct++)
        #pragma unroll
        for (int r=0;r<4;r++)
          cb[(mt*16 + g*4 + r)*65 + ct*16 + l15] = acc[mt][ct][r];
  }
  __syncthreads();
  if (ks == 0){
    float4v lv[2];
    #pragma unroll
    for (int mt=0;mt<2;mt++) lv[mt] = *(float4v*)(lst + mt*16 + g*4);
    #pragma unroll
    for (int mt=0;mt<2;mt++)
      #pragma unroll
      for (int ct=0;ct<4;ct++)
        #pragma unroll
        for (int r=0;r<4;r++){
          int idx = (mt*16 + g*4 + r)*65 + ct*16 + l15;
          cb[idx] = (acc[mt][ct][r] + cb[idx]) / lv[mt][r];
        }
  }
  __syncthreads();
  float gm = gamma_p[0];
  int m31 = lane & 31, ch = lane >> 5;
  const float* xr = x1u + (size_t)(b*C_ + cq*64 + ks*32)*N_ + mblk*32;
  float* orow = out + (size_t)(b*C_ + cq*64 + ks*32)*N_ + mblk*32;
  #pragma unroll 8
  for (int i=0; i<16; i++){
    int c_l = i*2 + ch;                      // 32 c-rows per wave, 2 per step
    float v = cb[m31*65 + ks*32 + c_l];
    orow[(size_t)c_l*N_ + m31] = gm*v + xr[(size_t)c_l*N_ + m31];
  }
}

extern "C" void kernel_launch(void* const* d_in, const int* in_sizes, int n_in,
                              void* d_out, int out_size, void* d_ws, size_t ws_size,
                              hipStream_t stream){
  (void)in_sizes; (void)n_in; (void)out_size; (void)ws_size;
  const float* x1 = (const float*)d_in[0];
  const float* x2 = (const float*)d_in[1];
  const float* wq = (const float*)d_in[2];
  const float* wk = (const float*)d_in[3];
  const float* wv = (const float*)d_in[4];
  const float* gq = (const float*)d_in[5];
  const float* bq = (const float*)d_in[6];
  const float* mq = (const float*)d_in[7];
  const float* vq = (const float*)d_in[8];
  const float* gk = (const float*)d_in[9];
  const float* bk = (const float*)d_in[10];
  const float* mk = (const float*)d_in[11];
  const float* vk = (const float*)d_in[12];
  const float* gv = (const float*)d_in[13];
  const float* bv = (const float*)d_in[14];
  const float* mv = (const float*)d_in[15];
  const float* vv = (const float*)d_in[16];
  const float* gamma = (const float*)d_in[17];
  float* out = (float*)d_out;

  char* p = (char*)d_ws;
  float* x1u          = (float*)p;          p += (size_t)B_*C_*N_*4;   // 16 MB
  unsigned short* Qb  = (unsigned short*)p; p += (size_t)B_*N_*32*2;   // 1 MB
  unsigned short* Kb  = (unsigned short*)p; p += (size_t)B_*N_*32*2;   // 1 MB
  unsigned short* Vb  = (unsigned short*)p; p += (size_t)B_*C_*N_*2;   // 8 MB
  unsigned short* wqb = (unsigned short*)p; p += 32*256*2;
  unsigned short* wkb = (unsigned short*)p; p += 32*256*2;
  unsigned short* wvb = (unsigned short*)p; p += 256*256*2;
  float* biasq        = (float*)p;          p += 32*4;
  float* biask        = (float*)p;          p += 32*4;
  float* biasv        = (float*)p;          p += 256*4;

  fold_w_kernel<<<256, 256, 0, stream>>>(wq,wk,wv,gq,bq,mq,vq,gk,bk,mk,vk,gv,bv,mv,vv,
                                         wqb,wkb,wvb,biasq,biask,biasv);
  pre_kernel<<<dim3(128,4,2), 256, 0, stream>>>(x1, x2, wqb, wkb, wvb,
                                                biasq, biask, biasv, x1u, Qb, Kb, Vb);
  attn_kernel<<<dim3(128,4), 512, 0, stream>>>(Qb, Kb, Vb, x1u, gamma, out);
}

// Round 14
// 143.266 us; speedup vs baseline: 1.9604x; 1.1570x over previous
//
#include <hip/hip_runtime.h>

#define B_ 4
#define C_ 256
#define N_ 4096
#define LOG2E 1.4426950408889634f

typedef short short8 __attribute__((ext_vector_type(8)));
typedef short short4_ __attribute__((ext_vector_type(4)));
typedef float float4v __attribute__((ext_vector_type(4)));
typedef unsigned int uint2v __attribute__((ext_vector_type(2)));
typedef unsigned int u32;

__device__ inline unsigned short f2b(float x){
  unsigned u = __builtin_bit_cast(unsigned, x);
  u = u + 0x7FFFu + ((u >> 16) & 1u);
  return (unsigned short)(u >> 16);
}

__device__ inline u32 cvtpk(float lo, float hi){
  u32 r; asm("v_cvt_pk_bf16_f32 %0, %1, %2" : "=v"(r) : "v"(lo), "v"(hi)); return r;
}

__device__ inline void gload16(const void* g, void* l){
  __builtin_amdgcn_global_load_lds((const __attribute__((address_space(1))) u32*)g,
                                   (__attribute__((address_space(3))) u32*)l, 16, 0, 0);
}

// ---------------- fold BN into weights (log2e folded into Q path) ----------------
__global__ void fold_w_kernel(const float* __restrict__ wq, const float* __restrict__ wk,
    const float* __restrict__ wv,
    const float* gq, const float* bq, const float* mq, const float* vq,
    const float* gk, const float* bk, const float* mk, const float* vk,
    const float* gv, const float* bv, const float* mv, const float* vv,
    unsigned short* wqb, unsigned short* wkb, unsigned short* wvb,
    float* biasq, float* biask, float* biasv){
  int i = blockIdx.x*256 + threadIdx.x;   // 65536 threads
  int o = i >> 8;
  float sv = gv[o]*rsqrtf(vv[o]+1e-5f);
  wvb[i] = f2b(wv[i]*sv);
  if (i < 32*256){
    int oq = i >> 8;
    float sq = gq[oq]*rsqrtf(vq[oq]+1e-5f);
    wqb[i] = f2b(wq[i]*sq*LOG2E);
    float sk = gk[oq]*rsqrtf(vk[oq]+1e-5f);
    wkb[i] = f2b(wk[i]*sk);
  }
  if (i < 256) biasv[i] = bv[i] - mv[i]*(gv[i]*rsqrtf(vv[i]+1e-5f));
  if (i < 32){
    biasq[i] = (bq[i] - mq[i]*(gq[i]*rsqrtf(vq[i]+1e-5f)))*LOG2E;
    biask[i] = bk[i] - mk[i]*(gk[i]*rsqrtf(vk[i]+1e-5f));
  }
}

// ------- preprocessing: z=0 upsample+Qconv ; z=1 x2 stage+K+V[0:128) ; z=2 x2 stage+V[128:256) -------
__global__ __launch_bounds__(256, 2)
void pre_kernel(const float* __restrict__ x1, const float* __restrict__ x2,
                const unsigned short* __restrict__ wqb,
                const unsigned short* __restrict__ wkb,
                const unsigned short* __restrict__ wvb,
                const float* __restrict__ biasq, const float* __restrict__ biask,
                const float* __restrict__ biasv,
                float* __restrict__ x1u,
                unsigned short* __restrict__ Qb, unsigned short* __restrict__ Kb,
                unsigned short* __restrict__ Vb){
  __shared__ unsigned short xt[64*260];
  int b = blockIdx.y;
  int t = threadIdx.x;
  int lane = t&63, w = t>>6, l15 = lane&15, g = lane>>4;

  if (blockIdx.z == 0){
    int y = blockIdx.x;
    float fy = 0.5f*y - 0.25f;
    float y0f = floorf(fy); float wy = fy - y0f;
    int y0 = max(0,min(31,(int)y0f)), y1 = max(0,min(31,(int)y0f+1));
    int x = t & 63, cg = t >> 6;
    float fx = 0.5f*x - 0.25f;
    float x0f = floorf(fx); float wx = fx - x0f;
    int x0 = max(0,min(31,(int)x0f)), x1i = max(0,min(31,(int)x0f+1));
    #pragma unroll 8
    for (int i=0;i<64;i++){
      int c = cg + i*4;
      const float* s0 = x1 + ((size_t)(b*C_ + c)*32 + y0)*32;
      const float* s1 = x1 + ((size_t)(b*C_ + c)*32 + y1)*32;
      float v00=s0[x0], v01=s0[x1i], v10=s1[x0], v11=s1[x1i];
      float v0 = v00 + wx*(v01-v00), v1 = v10 + wx*(v11-v10);
      float val = v0 + wy*(v1-v0);
      x1u[(size_t)(b*C_ + c)*N_ + y*64 + x] = val;
      xt[x*260 + c] = f2b(val);
    }
    __syncthreads();
    const unsigned short* arow = xt + (w*16+l15)*260 + g*8;
    short8 a[8];
    #pragma unroll
    for (int kk=0;kk<8;kk++){
      short4_ lo = *(const short4_*)(arow + kk*32);
      short4_ hi = *(const short4_*)(arow + kk*32 + 4);
      short8 af;
      af[0]=lo[0];af[1]=lo[1];af[2]=lo[2];af[3]=lo[3];
      af[4]=hi[0];af[5]=hi[1];af[6]=hi[2];af[7]=hi[3];
      a[kk]=af;
    }
    #pragma unroll
    for (int ot=0; ot<2; ot++){
      int o = ot*16 + l15;
      const unsigned short* wrow = wqb + o*C_ + g*8;
      float4v acc = {0.f,0.f,0.f,0.f};
      #pragma unroll
      for (int kk=0;kk<8;kk++){
        short8 bf = *(const short8*)(wrow + kk*32);
        acc = __builtin_amdgcn_mfma_f32_16x16x32_bf16(a[kk], bf, acc, 0,0,0);
      }
      float bs = biasq[o];
      #pragma unroll
      for (int r=0;r<4;r++){
        float yv = acc[r] + bs;
        yv = yv >= 0.f ? yv : 0.1f*yv;
        int m = y*64 + w*16 + g*4 + r;
        Qb[(size_t)(b*N_+m)*32 + o] = f2b(yv);
      }
    }
  } else {
    int n0 = blockIdx.x*64;
    int n = t & 63, cg = t >> 6;
    #pragma unroll 8
    for (int i=0;i<64;i++){
      int c = cg + i*4;
      float v = x2[(size_t)(b*C_ + c)*N_ + n0 + n];
      xt[n*260 + c] = f2b(v);
    }
    __syncthreads();
    const unsigned short* arow = xt + (w*16+l15)*260 + g*8;
    short8 a[8];
    #pragma unroll
    for (int kk=0;kk<8;kk++){
      short4_ lo = *(const short4_*)(arow + kk*32);
      short4_ hi = *(const short4_*)(arow + kk*32 + 4);
      short8 af;
      af[0]=lo[0];af[1]=lo[1];af[2]=lo[2];af[3]=lo[3];
      af[4]=hi[0];af[5]=hi[1];af[6]=hi[2];af[7]=hi[3];
      a[kk]=af;
    }
    if (blockIdx.z == 1){
      #pragma unroll
      for (int ot=0; ot<2; ot++){
        int o = ot*16 + l15;
        const unsigned short* wrow = wkb + o*C_ + g*8;
        float4v acc = {0.f,0.f,0.f,0.f};
        #pragma unroll
        for (int kk=0;kk<8;kk++){
          short8 bf = *(const short8*)(wrow + kk*32);
          acc = __builtin_amdgcn_mfma_f32_16x16x32_bf16(a[kk], bf, acc, 0,0,0);
        }
        float bs = biask[o];
        #pragma unroll
        for (int r=0;r<4;r++){
          float yv = acc[r] + bs;
          yv = yv >= 0.f ? yv : 0.1f*yv;
          int m = n0 + w*16 + g*4 + r;
          Kb[(size_t)(b*N_+m)*32 + o] = f2b(yv);
        }
      }
    }
    int obase = (blockIdx.z == 1) ? 0 : 8;
    #pragma unroll
    for (int ot=0; ot<8; ot++){
      int o = (obase + ot)*16 + l15;
      const unsigned short* wrow = wvb + (size_t)o*C_ + g*8;
      float4v acc = {0.f,0.f,0.f,0.f};
      #pragma unroll
      for (int kk=0;kk<8;kk++){
        short8 bf = *(const short8*)(wrow + kk*32);
        acc = __builtin_amdgcn_mfma_f32_16x16x32_bf16(a[kk], bf, acc, 0,0,0);
      }
      float bs = biasv[o];
      #pragma unroll
      for (int r=0;r<4;r++){
        float yv = acc[r] + bs;
        yv = yv >= 0.f ? yv : 0.1f*yv;
        int m = n0 + w*16 + g*4 + r;
        Vb[(size_t)(b*C_ + o)*N_ + m] = f2b(yv);
      }
    }
  }
}

// ---------------- fused flash attention + gamma*out + x1u ----------------
// Grid 256 (XCD-swizzled), 512 threads (8 waves), M=64/block, full-n sweep.
// cq = w&3 (c-range 64), ks = w>>2 (k-half 32). Waves 0-3 own softmax of 16-row
// tile w (pipelined one tile ahead, P/flags/scl parity dbuf).
// V [256c][64n] staged via global_load_lds into a TRIPLE buffer, prefetched
// TWO tiles ahead; barriers are raw s_barrier with COUNTED vmcnt (loads stay in
// flight across barriers -- no vmcnt(0) drain). lgkmcnt(0) publishes P.
__global__ __launch_bounds__(512, 2)
void attn_kernel(const unsigned short* __restrict__ Qb,
                 const unsigned short* __restrict__ Kb,
                 const unsigned short* __restrict__ Vb,
                 const float* __restrict__ x1u,
                 const float* __restrict__ gamma_p,
                 float* __restrict__ out){
  // [0,98304): V tri-buffer (3 x 32768) | epilogue cbuf[4 cq][64 m][65] f32 = [0,66560)
  // [98304,114688): P parity dbuf (2 x 4 tiles x 2048)
  // 114688: flags[2][4] ; 114720: scl[2][64] f32 ; 115232: lst[64] f32
  __shared__ __align__(16) char smem[115488];
  int* flagsB = (int*)(smem + 114688);
  float* sclB = (float*)(smem + 114720);
  float* lst  = (float*)(smem + 115232);

  int wg = blockIdx.y*64 + blockIdx.x;
  int id = (wg & 7)*32 + (wg >> 3);           // bijective XCD swizzle (256 = 8*32)
  int b = id >> 6, mblk = id & 63;
  int t = threadIdx.x, lane = t & 63, w = t >> 6;
  int l15 = lane & 15, g = lane >> 4;
  int swz = (l15 & 7) << 4;
  int cq = w & 3, ks = w >> 2;

  short8 qf{};
  if (w < 4)
    qf = *(const short8*)(Qb + (size_t)(b*N_ + mblk*64 + w*16 + l15)*32 + g*8);

  float4v acc[4][4];   // [mt][ct] : 64 m x 64 c partial (k-half ks)
  #pragma unroll
  for (int mt=0;mt<4;mt++)
    #pragma unroll
    for (int ct=0;ct<4;ct++) acc[mt][ct] = (float4v){0.f,0.f,0.f,0.f};
  float mrow = -1e30f, lrun = 0.f;
  const float4v zero4 = {0.f,0.f,0.f,0.f};

  // V staging: 2048 16B chunks over 512 threads -> 4 each (linear LDS, inv-swz src)
  u32 goff[4]; int loff[4];
  #pragma unroll
  for (int j=0;j<4;j++){
    int i = j*512 + t;
    int c = i >> 3, jj = i & 7;
    loff[j] = i*16;
    goff[j] = (u32)(c*(N_*2)) + (u32)((jj ^ (c & 7)) << 4);
  }
  const char* Vbyte = (const char*)Vb + (size_t)b*C_*N_*2;
  const short* kbase = (const short*)Kb + (size_t)(b*N_ + l15)*32 + g*8;

  auto stageV = [&](int u){                      // stage tile u into buf[u%3]
    const char* src = Vbyte + u*128;
    char* buf = smem + (u%3)*32768;
    #pragma unroll
    for (int j=0;j<4;j++) gload16(src + goff[j], buf + loff[j]);
  };
  auto loadK = [&](short8 (&kf)[4], int tt){
    const short* kp = kbase + (size_t)tt*64*32;
    #pragma unroll
    for (int j=0;j<4;j++) kf[j] = *(const short8*)(kp + j*512);
  };

  // QK(tile)+softmax -> P/flags/scl parity buffer pdst (single phase)
  auto softmax_step = [&](const short8 (&kf)[4], int pdst){
    float4v s[4];
    #pragma unroll
    for (int j=0;j<4;j++)
      s[j] = __builtin_amdgcn_mfma_f32_16x16x32_bf16(kf[j], qf, zero4, 0, 0, 0);
    float tmax = fmaxf(fmaxf(fmaxf(s[0][0],s[0][1]),fmaxf(s[0][2],s[0][3])),
               fmaxf(fmaxf(fmaxf(s[1][0],s[1][1]),fmaxf(s[1][2],s[1][3])),
               fmaxf(fmaxf(fmaxf(s[2][0],s[2][1]),fmaxf(s[2][2],s[2][3])),
                     fmaxf(fmaxf(s[3][0],s[3][1]),fmaxf(s[3][2],s[3][3])))));
    int trig = __any((tmax > mrow + 8.f) ? 1 : 0) ? 1 : 0;
    if (lane == 0) flagsB[pdst*4 + w] = trig;
    if (trig){
      float tm = fmaxf(tmax, __shfl_xor(tmax, 16));
      tm = fmaxf(tm, __shfl_xor(tm, 32));
      float mnew = fmaxf(mrow, tm);
      float sc = exp2f(mrow - mnew);
      mrow = mnew; lrun *= sc;
      if (lane < 16) sclB[pdst*64 + w*16 + l15] = sc;
    }
    char* pw = smem + 98304 + pdst*8192 + w*2048 + l15*128;
    #pragma unroll
    for (int j=0;j<4;j++){
      float p0 = exp2f(s[j][0]-mrow), p1 = exp2f(s[j][1]-mrow);
      float p2 = exp2f(s[j][2]-mrow), p3 = exp2f(s[j][3]-mrow);
      lrun += (p0+p1)+(p2+p3);
      u32 lo = cvtpk(p0, p1);
      u32 hi = cvtpk(p2, p3);
      *(uint2v*)(pw + ((j*32 + g*8) ^ swz)) = (uint2v){lo, hi};
    }
  };

  auto body = [&](int tt, short8 (&kC)[4], short8 (&kN)[4]){
    int pp = tt & 1;
    if (tt < 62) stageV(tt+2);                 // 2-deep prefetch
    if (w < 4){
      loadK(kN, (tt+2) & 63);                  // K prefetch (wrap harmless)
      if (tt < 63) softmax_step(kC, pp ^ 1);   // P(t+1)
    }
    // rescale partials with flags/scl of P(t)
    #pragma unroll
    for (int mt=0;mt<4;mt++){
      if (flagsB[pp*4 + mt]){
        float4v sv = *(float4v*)(sclB + pp*64 + mt*16 + g*4);
        #pragma unroll
        for (int ct=0;ct<4;ct++){
          acc[mt][ct][0]*=sv[0]; acc[mt][ct][1]*=sv[1];
          acc[mt][ct][2]*=sv[2]; acc[mt][ct][3]*=sv[3];
        }
      }
    }
    // PV(t): k-half ks, c-range cq*64
    int ko = (ks*64 + g*16) ^ swz;
    const char* vbc = smem + (tt%3)*32768;
    const char* pbase = smem + 98304 + pp*8192;
    short8 pa[4], vf[4];
    #pragma unroll
    for (int mt=0;mt<4;mt++)
      pa[mt] = *(const short8*)(pbase + mt*2048 + l15*128 + ko);
    #pragma unroll
    for (int ct=0;ct<4;ct++)
      vf[ct] = *(const short8*)(vbc + (cq*64 + ct*16 + l15)*128 + ko);
    __builtin_amdgcn_s_setprio(1);
    #pragma unroll
    for (int mt=0;mt<4;mt++)
      #pragma unroll
      for (int ct=0;ct<4;ct++)
        acc[mt][ct] = __builtin_amdgcn_mfma_f32_16x16x32_bf16(pa[mt], vf[ct], acc[mt][ct], 0, 0, 0);
    __builtin_amdgcn_s_setprio(0);
    // ---- counted-vmcnt raw barrier: stage(t+1) must be drained; stage(t+2)+K(t+2) stay in flight ----
    if (w < 4){
      if (tt < 62) asm volatile("s_waitcnt lgkmcnt(0) vmcnt(8)" ::: "memory");
      else         asm volatile("s_waitcnt lgkmcnt(0) vmcnt(4)" ::: "memory");
    } else {
      if (tt < 62) asm volatile("s_waitcnt lgkmcnt(0) vmcnt(4)" ::: "memory");
      else         asm volatile("s_waitcnt lgkmcnt(0) vmcnt(0)" ::: "memory");
    }
    __builtin_amdgcn_s_barrier();
    __builtin_amdgcn_sched_barrier(0);
  };

  // prologue: stage V(0),V(1); softmax(0) -> P parity 0; kA = K(1)
  short8 kA[4], kB[4];
  stageV(0);
  stageV(1);
  if (w < 4){
    short8 k0[4];
    loadK(k0, 0);
    softmax_step(k0, 0);
    loadK(kA, 1);
    asm volatile("s_waitcnt lgkmcnt(0) vmcnt(8)" ::: "memory");
  } else {
    asm volatile("s_waitcnt lgkmcnt(0) vmcnt(4)" ::: "memory");
  }
  __builtin_amdgcn_s_barrier();
  __builtin_amdgcn_sched_barrier(0);

  for (int tt=0; tt<64; tt+=2){
    body(tt,   kA, kB);
    body(tt+1, kB, kA);
  }

  // ---------- epilogue: l-reduce, k-partial combine, normalize, store ----------
  if (w < 4){
    lrun += __shfl_xor(lrun, 16);
    lrun += __shfl_xor(lrun, 32);
    if (lane < 16) lst[w*16 + l15] = lrun;
  }
  float* cb = (float*)smem + cq*4160;   // [64 m][65] f32 per cq (overlays V bufs)
  if (ks == 1){
    #pragma unroll
    for (int mt=0;mt<4;mt++)
      #pragma unroll
      for (int ct=0;ct<4;ct++)
        #pragma unroll
        for (int r=0;r<4;r++)
          cb[(mt*16 + g*4 + r)*65 + ct*16 + l15] = acc[mt][ct][r];
  }
  __syncthreads();
  if (ks == 0){
    float4v lv[4];
    #pragma unroll
    for (int mt=0;mt<4;mt++) lv[mt] = *(float4v*)(lst + mt*16 + g*4);
    #pragma unroll
    for (int mt=0;mt<4;mt++)
      #pragma unroll
      for (int ct=0;ct<4;ct++)
        #pragma unroll
        for (int r=0;r<4;r++){
          int idx = (mt*16 + g*4 + r)*65 + ct*16 + l15;
          cb[idx] = (acc[mt][ct][r] + cb[idx]) / lv[mt][r];
        }
  }
  __syncthreads();
  float gm = gamma_p[0];
  const float* xr = x1u + (size_t)(b*C_ + cq*64 + ks*32)*N_ + mblk*64;
  float* orow = out + (size_t)(b*C_ + cq*64 + ks*32)*N_ + mblk*64;
  #pragma unroll 8
  for (int i=0; i<32; i++){
    int c_l = ks*32 + i;
    float v = cb[lane*65 + c_l];
    orow[(size_t)i*N_ + lane] = gm*v + xr[(size_t)i*N_ + lane];
  }
}

extern "C" void kernel_launch(void* const* d_in, const int* in_sizes, int n_in,
                              void* d_out, int out_size, void* d_ws, size_t ws_size,
                              hipStream_t stream){
  (void)in_sizes; (void)n_in; (void)out_size; (void)ws_size;
  const float* x1 = (const float*)d_in[0];
  const float* x2 = (const float*)d_in[1];
  const float* wq = (const float*)d_in[2];
  const float* wk = (const float*)d_in[3];
  const float* wv = (const float*)d_in[4];
  const float* gq = (const float*)d_in[5];
  const float* bq = (const float*)d_in[6];
  const float* mq = (const float*)d_in[7];
  const float* vq = (const float*)d_in[8];
  const float* gk = (const float*)d_in[9];
  const float* bk = (const float*)d_in[10];
  const float* mk = (const float*)d_in[11];
  const float* vk = (const float*)d_in[12];
  const float* gv = (const float*)d_in[13];
  const float* bv = (const float*)d_in[14];
  const float* mv = (const float*)d_in[15];
  const float* vv = (const float*)d_in[16];
  const float* gamma = (const float*)d_in[17];
  float* out = (float*)d_out;

  char* p = (char*)d_ws;
  float* x1u          = (float*)p;          p += (size_t)B_*C_*N_*4;   // 16 MB
  unsigned short* Qb  = (unsigned short*)p; p += (size_t)B_*N_*32*2;   // 1 MB
  unsigned short* Kb  = (unsigned short*)p; p += (size_t)B_*N_*32*2;   // 1 MB
  unsigned short* Vb  = (unsigned short*)p; p += (size_t)B_*C_*N_*2;   // 8 MB
  unsigned short* wqb = (unsigned short*)p; p += 32*256*2;
  unsigned short* wkb = (unsigned short*)p; p += 32*256*2;
  unsigned short* wvb = (unsigned short*)p; p += 256*256*2;
  float* biasq        = (float*)p;          p += 32*4;
  float* biask        = (float*)p;          p += 32*4;
  float* biasv        = (float*)p;          p += 256*4;

  fold_w_kernel<<<256, 256, 0, stream>>>(wq,wk,wv,gq,bq,mq,vq,gk,bk,mk,vk,gv,bv,mv,vv,
                                         wqb,wkb,wvb,biasq,biask,biasv);
  pre_kernel<<<dim3(64,4,3), 256, 0, stream>>>(x1, x2, wqb, wkb, wvb,
                                               biasq, biask, biasv, x1u, Qb, Kb, Vb);
  attn_kernel<<<dim3(64,4), 512, 0, stream>>>(Qb, Kb, Vb, x1u, gamma, out);
}

// Round 15
// 109.349 us; speedup vs baseline: 2.5685x; 1.3102x over previous
//
#include <hip/hip_runtime.h>

#define B_ 4
#define C_ 256
#define N_ 4096
#define LOG2E 1.4426950408889634f

typedef short short8 __attribute__((ext_vector_type(8)));
typedef short short4_ __attribute__((ext_vector_type(4)));
typedef float float4v __attribute__((ext_vector_type(4)));
typedef unsigned int uint2v __attribute__((ext_vector_type(2)));
typedef unsigned int u32;

__device__ inline unsigned short f2b(float x){
  unsigned u = __builtin_bit_cast(unsigned, x);
  u = u + 0x7FFFu + ((u >> 16) & 1u);
  return (unsigned short)(u >> 16);
}
__device__ inline float b2f(unsigned short s){
  return __builtin_bit_cast(float, ((u32)s) << 16);
}
__device__ inline u32 cvtpk(float lo, float hi){
  u32 r; asm("v_cvt_pk_bf16_f32 %0, %1, %2" : "=v"(r) : "v"(lo), "v"(hi)); return r;
}
__device__ inline void gload16(const void* g, void* l){
  __builtin_amdgcn_global_load_lds((const __attribute__((address_space(1))) u32*)g,
                                   (__attribute__((address_space(3))) u32*)l, 16, 0, 0);
}

// ---------------- fold BN into weights (log2e folded into Q path) ----------------
__global__ void fold_w_kernel(const float* __restrict__ wq, const float* __restrict__ wk,
    const float* __restrict__ wv,
    const float* gq, const float* bq, const float* mq, const float* vq,
    const float* gk, const float* bk, const float* mk, const float* vk,
    const float* gv, const float* bv, const float* mv, const float* vv,
    unsigned short* wqb, unsigned short* wkb, unsigned short* wvb,
    float* biasq, float* biask, float* biasv){
  int i = blockIdx.x*256 + threadIdx.x;   // 65536 threads
  int o = i >> 8;
  float sv = gv[o]*rsqrtf(vv[o]+1e-5f);
  wvb[i] = f2b(wv[i]*sv);
  if (i < 32*256){
    int oq = i >> 8;
    float sq = gq[oq]*rsqrtf(vq[oq]+1e-5f);
    wqb[i] = f2b(wq[i]*sq*LOG2E);
    float sk = gk[oq]*rsqrtf(vk[oq]+1e-5f);
    wkb[i] = f2b(wk[i]*sk);
  }
  if (i < 256) biasv[i] = bv[i] - mv[i]*(gv[i]*rsqrtf(vv[i]+1e-5f));
  if (i < 32){
    biasq[i] = (bq[i] - mq[i]*(gq[i]*rsqrtf(vq[i]+1e-5f)))*LOG2E;
    biask[i] = bk[i] - mk[i]*(gk[i]*rsqrtf(vk[i]+1e-5f));
  }
}

// ------- preprocessing: z=0 upsample+Qconv ; z=1 x2 stage+K+V[0:128) ; z=2 x2 stage+V[128:256) -------
__global__ __launch_bounds__(256, 2)
void pre_kernel(const float* __restrict__ x1, const float* __restrict__ x2,
                const unsigned short* __restrict__ wqb,
                const unsigned short* __restrict__ wkb,
                const unsigned short* __restrict__ wvb,
                const float* __restrict__ biasq, const float* __restrict__ biask,
                const float* __restrict__ biasv,
                float* __restrict__ x1u,
                unsigned short* __restrict__ Qb, unsigned short* __restrict__ Kb,
                unsigned short* __restrict__ Vb){
  __shared__ unsigned short xt[64*260];
  int b = blockIdx.y;
  int t = threadIdx.x;
  int lane = t&63, w = t>>6, l15 = lane&15, g = lane>>4;

  if (blockIdx.z == 0){
    int y = blockIdx.x;
    float fy = 0.5f*y - 0.25f;
    float y0f = floorf(fy); float wy = fy - y0f;
    int y0 = max(0,min(31,(int)y0f)), y1 = max(0,min(31,(int)y0f+1));
    int x = t & 63, cg = t >> 6;
    float fx = 0.5f*x - 0.25f;
    float x0f = floorf(fx); float wx = fx - x0f;
    int x0 = max(0,min(31,(int)x0f)), x1i = max(0,min(31,(int)x0f+1));
    #pragma unroll 8
    for (int i=0;i<64;i++){
      int c = cg + i*4;
      const float* s0 = x1 + ((size_t)(b*C_ + c)*32 + y0)*32;
      const float* s1 = x1 + ((size_t)(b*C_ + c)*32 + y1)*32;
      float v00=s0[x0], v01=s0[x1i], v10=s1[x0], v11=s1[x1i];
      float v0 = v00 + wx*(v01-v00), v1 = v10 + wx*(v11-v10);
      float val = v0 + wy*(v1-v0);
      x1u[(size_t)(b*C_ + c)*N_ + y*64 + x] = val;
      xt[x*260 + c] = f2b(val);
    }
    __syncthreads();
    const unsigned short* arow = xt + (w*16+l15)*260 + g*8;
    short8 a[8];
    #pragma unroll
    for (int kk=0;kk<8;kk++){
      short4_ lo = *(const short4_*)(arow + kk*32);
      short4_ hi = *(const short4_*)(arow + kk*32 + 4);
      short8 af;
      af[0]=lo[0];af[1]=lo[1];af[2]=lo[2];af[3]=lo[3];
      af[4]=hi[0];af[5]=hi[1];af[6]=hi[2];af[7]=hi[3];
      a[kk]=af;
    }
    #pragma unroll
    for (int ot=0; ot<2; ot++){
      int o = ot*16 + l15;
      const unsigned short* wrow = wqb + o*C_ + g*8;
      float4v acc = {0.f,0.f,0.f,0.f};
      #pragma unroll
      for (int kk=0;kk<8;kk++){
        short8 bf = *(const short8*)(wrow + kk*32);
        acc = __builtin_amdgcn_mfma_f32_16x16x32_bf16(a[kk], bf, acc, 0,0,0);
      }
      float bs = biasq[o];
      #pragma unroll
      for (int r=0;r<4;r++){
        float yv = acc[r] + bs;
        yv = yv >= 0.f ? yv : 0.1f*yv;
        int m = y*64 + w*16 + g*4 + r;
        Qb[(size_t)(b*N_+m)*32 + o] = f2b(yv);
      }
    }
  } else {
    int n0 = blockIdx.x*64;
    int n = t & 63, cg = t >> 6;
    #pragma unroll 8
    for (int i=0;i<64;i++){
      int c = cg + i*4;
      float v = x2[(size_t)(b*C_ + c)*N_ + n0 + n];
      xt[n*260 + c] = f2b(v);
    }
    __syncthreads();
    const unsigned short* arow = xt + (w*16+l15)*260 + g*8;
    short8 a[8];
    #pragma unroll
    for (int kk=0;kk<8;kk++){
      short4_ lo = *(const short4_*)(arow + kk*32);
      short4_ hi = *(const short4_*)(arow + kk*32 + 4);
      short8 af;
      af[0]=lo[0];af[1]=lo[1];af[2]=lo[2];af[3]=lo[3];
      af[4]=hi[0];af[5]=hi[1];af[6]=hi[2];af[7]=hi[3];
      a[kk]=af;
    }
    if (blockIdx.z == 1){
      #pragma unroll
      for (int ot=0; ot<2; ot++){
        int o = ot*16 + l15;
        const unsigned short* wrow = wkb + o*C_ + g*8;
        float4v acc = {0.f,0.f,0.f,0.f};
        #pragma unroll
        for (int kk=0;kk<8;kk++){
          short8 bf = *(const short8*)(wrow + kk*32);
          acc = __builtin_amdgcn_mfma_f32_16x16x32_bf16(a[kk], bf, acc, 0,0,0);
        }
        float bs = biask[o];
        #pragma unroll
        for (int r=0;r<4;r++){
          float yv = acc[r] + bs;
          yv = yv >= 0.f ? yv : 0.1f*yv;
          int m = n0 + w*16 + g*4 + r;
          Kb[(size_t)(b*N_+m)*32 + o] = f2b(yv);
        }
      }
    }
    int obase = (blockIdx.z == 1) ? 0 : 8;
    #pragma unroll
    for (int ot=0; ot<8; ot++){
      int o = (obase + ot)*16 + l15;
      const unsigned short* wrow = wvb + (size_t)o*C_ + g*8;
      float4v acc = {0.f,0.f,0.f,0.f};
      #pragma unroll
      for (int kk=0;kk<8;kk++){
        short8 bf = *(const short8*)(wrow + kk*32);
        acc = __builtin_amdgcn_mfma_f32_16x16x32_bf16(a[kk], bf, acc, 0,0,0);
      }
      float bs = biasv[o];
      #pragma unroll
      for (int r=0;r<4;r++){
        float yv = acc[r] + bs;
        yv = yv >= 0.f ? yv : 0.1f*yv;
        int m = n0 + w*16 + g*4 + r;
        Vb[(size_t)(b*C_ + o)*N_ + m] = f2b(yv);
      }
    }
  }
}

// ---------------- flash attention partial (n-split): writes bf16 partial + (m,l) stats ----------------
// Grid 512 (XCD-swizzled: 64 mblk x 4 b x 2 ng), 512 threads (8 waves).
// Block: M=64 rows (mblk), n in [ng*2048, +2048), KVBLK=32 -> 64 iters, 1 barrier/iter.
// LDS 43.5 KB (V dbuf 2x16K + P parity 2x4x1280 + flags/scl) -> 2 blocks/CU target.
// Waves 0-3: softmax of 16-row tile w (pipelined 1 tile ahead). All 8 waves:
// PV c-split (w*32, 32 channels), full k=32. acc[4mt][2ct].
__global__ __launch_bounds__(512, 2)
void attn_kernel(const unsigned short* __restrict__ Qb,
                 const unsigned short* __restrict__ Kb,
                 const unsigned short* __restrict__ Vb,
                 unsigned short* __restrict__ partial,
                 float* __restrict__ statsg){
  // [0,32768): V dbuf (2 x 16384, 64B rows, slot^(c&3) swizzle)
  // [32768,43008): P parity (2 x 4 tiles x 16 rows x 80B)  -- 80B stride: aligned + conflict-free
  // 43008: flags[2][4] int ; 43040: scl[2][64] f32
  __shared__ __align__(16) char smem[43552];
  int* flagsB = (int*)(smem + 43008);
  float* sclB = (float*)(smem + 43040);

  int wg = (blockIdx.z*4 + blockIdx.y)*64 + blockIdx.x;
  int id = (wg & 7)*64 + (wg >> 3);            // bijective XCD swizzle (512 = 8*64)
  int ng = id >> 8, b = (id >> 6) & 3, mblk = id & 63;
  int t = threadIdx.x, lane = t & 63, w = t >> 6;
  int l15 = lane & 15, g = lane >> 4;

  short8 qf{};
  if (w < 4)
    qf = *(const short8*)(Qb + (size_t)(b*N_ + mblk*64 + w*16 + l15)*32 + g*8);

  float4v acc[4][2];   // [mt][ct]: rows m=mt*16+g*4+r, cols c = w*32+ct*16+l15
  #pragma unroll
  for (int mt=0;mt<4;mt++)
    #pragma unroll
    for (int ct=0;ct<2;ct++) acc[mt][ct] = (float4v){0.f,0.f,0.f,0.f};
  float mrow = -1e30f, lrun = 0.f;
  const float4v zero4 = {0.f,0.f,0.f,0.f};

  // V staging: 1024 16B chunks over 512 threads -> 2 each (linear LDS, inv-swz source)
  u32 goff[2]; int loff[2];
  #pragma unroll
  for (int j=0;j<2;j++){
    int i = j*512 + t;
    int c = i >> 2, jj = i & 3;
    loff[j] = i*16;
    goff[j] = (u32)(c*(N_*2)) + (u32)((jj ^ (c & 3)) << 4);
  }
  const char* Vbyte = (const char*)Vb + (size_t)b*C_*N_*2 + ng*4096;
  const short* kbase = (const short*)Kb + (size_t)(b*N_ + ng*2048 + l15)*32 + g*8;

  auto stageV = [&](int tt, int par){
    const char* src = Vbyte + tt*64;
    #pragma unroll
    for (int j=0;j<2;j++) gload16(src + goff[j], smem + par*16384 + loff[j]);
  };
  auto loadK = [&](short8 (&kf)[2], int tt){
    const short* kp = kbase + (size_t)tt*1024;   // 32 rows x 32 D shorts
    #pragma unroll
    for (int j=0;j<2;j++) kf[j] = *(const short8*)(kp + j*512);
  };

  // QK(tile 32n) + online softmax -> P/flags/scl parity pdst
  auto softmax_step = [&](const short8 (&kf)[2], int pdst){
    float4v s[2];
    #pragma unroll
    for (int j=0;j<2;j++)
      s[j] = __builtin_amdgcn_mfma_f32_16x16x32_bf16(kf[j], qf, zero4, 0, 0, 0);
    float tmax = fmaxf(fmaxf(fmaxf(s[0][0],s[0][1]),fmaxf(s[0][2],s[0][3])),
                       fmaxf(fmaxf(s[1][0],s[1][1]),fmaxf(s[1][2],s[1][3])));
    int trig = __any((tmax > mrow + 8.f) ? 1 : 0) ? 1 : 0;
    if (lane == 0) flagsB[pdst*4 + w] = trig;
    if (trig){
      float tm = fmaxf(tmax, __shfl_xor(tmax, 16));
      tm = fmaxf(tm, __shfl_xor(tm, 32));
      float mnew = fmaxf(mrow, tm);
      float sc = exp2f(mrow - mnew);
      mrow = mnew; lrun *= sc;
      if (lane < 16) sclB[pdst*64 + w*16 + l15] = sc;
    }
    char* pw = smem + 32768 + pdst*5120 + w*1280 + l15*80;
    #pragma unroll
    for (int j=0;j<2;j++){
      float p0 = exp2f(s[j][0]-mrow), p1 = exp2f(s[j][1]-mrow);
      float p2 = exp2f(s[j][2]-mrow), p3 = exp2f(s[j][3]-mrow);
      lrun += (p0+p1)+(p2+p3);
      u32 lo = cvtpk(p0, p1);
      u32 hi = cvtpk(p2, p3);
      *(uint2v*)(pw + j*32 + g*8) = (uint2v){lo, hi};
    }
  };

  auto body = [&](int tt, short8 (&kC)[2], short8 (&kN)[2]){
    int pp = tt & 1, nx = (tt+1) & 1;
    if (tt < 63) stageV(tt+1, nx);
    if (w < 4){
      loadK(kN, (tt+2) & 63);
      if (tt < 63) softmax_step(kC, nx);
    }
    // rescale partials with flags/scl of tile t
    #pragma unroll
    for (int mt=0;mt<4;mt++){
      if (flagsB[pp*4 + mt]){
        float4v sv = *(float4v*)(sclB + pp*64 + mt*16 + g*4);
        #pragma unroll
        for (int ct=0;ct<2;ct++){
          acc[mt][ct][0]*=sv[0]; acc[mt][ct][1]*=sv[1];
          acc[mt][ct][2]*=sv[2]; acc[mt][ct][3]*=sv[3];
        }
      }
    }
    // PV(t): full k=32, c-range w*32
    const char* pb = smem + 32768 + pp*5120;
    const char* vbc = smem + pp*16384;
    short8 pa[4], vf[2];
    #pragma unroll
    for (int mt=0;mt<4;mt++)
      pa[mt] = *(const short8*)(pb + mt*1280 + l15*80 + g*16);
    #pragma unroll
    for (int ct=0;ct<2;ct++){
      int row = w*32 + ct*16 + l15;
      vf[ct] = *(const short8*)(vbc + row*64 + ((g*16) ^ ((row & 3) << 4)));
    }
    __builtin_amdgcn_s_setprio(1);
    #pragma unroll
    for (int mt=0;mt<4;mt++)
      #pragma unroll
      for (int ct=0;ct<2;ct++)
        acc[mt][ct] = __builtin_amdgcn_mfma_f32_16x16x32_bf16(pa[mt], vf[ct], acc[mt][ct], 0, 0, 0);
    __builtin_amdgcn_s_setprio(0);
    __syncthreads();   // drains stage DMA; publishes P(t+1)/flags/scl; V(t) reads done
  };

  // prologue
  short8 kA[2], kB[2];
  stageV(0, 0);
  if (w < 4){
    short8 k0[2];
    loadK(k0, 0);
    softmax_step(k0, 0);
    loadK(kA, 1);
  }
  __syncthreads();

  for (int tt=0; tt<64; tt+=2){
    body(tt,   kA, kB);
    body(tt+1, kB, kA);
  }

  // epilogue: stats + bf16 partial (no normalize; combine kernel merges ng halves)
  if (w < 4){
    lrun += __shfl_xor(lrun, 16);
    lrun += __shfl_xor(lrun, 32);
    if (lane < 16){
      int sidx = (((b*2+ng)*64 + mblk)*64 + w*16 + l15)*2;
      statsg[sidx] = mrow; statsg[sidx+1] = lrun;
    }
  }
  size_t pbg = (size_t)((b*2+ng)*64 + mblk)*16384;
  #pragma unroll
  for (int mt=0;mt<4;mt++)
    #pragma unroll
    for (int ct=0;ct<2;ct++)
      #pragma unroll
      for (int r=0;r<4;r++){
        int m = mt*16 + g*4 + r;
        int c = w*32 + ct*16 + l15;
        partial[pbg + m*256 + c] = f2b(acc[mt][ct][r]);
      }
}

// ---------------- combine: merge ng halves (softmax merge) + gamma*O/L + x1u ----------------
// grid (4 ctile, 64 mblk, 4 b), 256 thr. Transposes [m][c] partials to [c][m] output via LDS.
__global__ __launch_bounds__(256, 2)
void combine_kernel(const unsigned short* __restrict__ partial,
                    const float* __restrict__ statsg,
                    const float* __restrict__ x1u,
                    const float* __restrict__ gamma_p,
                    float* __restrict__ out){
  __shared__ float tile[64][65];
  __shared__ float fbuf[64][3];
  int b = blockIdx.z, mblk = blockIdx.y, ct4 = blockIdx.x;
  int t = threadIdx.x;
  float gm = gamma_p[0];
  if (t < 64){
    int s0 = (((b*2+0)*64 + mblk)*64 + t)*2;
    int s1 = (((b*2+1)*64 + mblk)*64 + t)*2;
    float m0 = statsg[s0], l0 = statsg[s0+1];
    float m1 = statsg[s1], l1 = statsg[s1+1];
    float M = fmaxf(m0, m1);
    float f0 = exp2f(m0 - M), f1 = exp2f(m1 - M);
    float L = l0*f0 + l1*f1;
    fbuf[t][0] = f0; fbuf[t][1] = f1; fbuf[t][2] = gm / L;
  }
  __syncthreads();
  size_t p0b = (size_t)((b*2+0)*64 + mblk)*16384 + ct4*64;
  size_t p1b = (size_t)((b*2+1)*64 + mblk)*16384 + ct4*64;
  int c_l = t & 63, mg = t >> 6;
  #pragma unroll 4
  for (int pass=0; pass<16; pass++){
    int m = pass*4 + mg;
    float v0 = b2f(partial[p0b + m*256 + c_l]);
    float v1 = b2f(partial[p1b + m*256 + c_l]);
    tile[m][c_l] = (v0*fbuf[m][0] + v1*fbuf[m][1]) * fbuf[m][2];
  }
  __syncthreads();
  int m = t & 63, cg = t >> 6;
  #pragma unroll 4
  for (int pass=0; pass<16; pass++){
    int c_l2 = pass*4 + cg;
    size_t gidx = ((size_t)(b*C_ + ct4*64 + c_l2))*N_ + mblk*64 + m;
    out[gidx] = tile[m][c_l2] + x1u[gidx];
  }
}

extern "C" void kernel_launch(void* const* d_in, const int* in_sizes, int n_in,
                              void* d_out, int out_size, void* d_ws, size_t ws_size,
                              hipStream_t stream){
  (void)in_sizes; (void)n_in; (void)out_size; (void)ws_size;
  const float* x1 = (const float*)d_in[0];
  const float* x2 = (const float*)d_in[1];
  const float* wq = (const float*)d_in[2];
  const float* wk = (const float*)d_in[3];
  const float* wv = (const float*)d_in[4];
  const float* gq = (const float*)d_in[5];
  const float* bq = (const float*)d_in[6];
  const float* mq = (const float*)d_in[7];
  const float* vq = (const float*)d_in[8];
  const float* gk = (const float*)d_in[9];
  const float* bk = (const float*)d_in[10];
  const float* mk = (const float*)d_in[11];
  const float* vk = (const float*)d_in[12];
  const float* gv = (const float*)d_in[13];
  const float* bv = (const float*)d_in[14];
  const float* mv = (const float*)d_in[15];
  const float* vv = (const float*)d_in[16];
  const float* gamma = (const float*)d_in[17];
  float* out = (float*)d_out;

  char* p = (char*)d_ws;
  float* x1u            = (float*)p;          p += (size_t)B_*C_*N_*4;      // 16 MB
  unsigned short* Qb    = (unsigned short*)p; p += (size_t)B_*N_*32*2;      // 1 MB
  unsigned short* Kb    = (unsigned short*)p; p += (size_t)B_*N_*32*2;      // 1 MB
  unsigned short* Vb    = (unsigned short*)p; p += (size_t)B_*C_*N_*2;      // 8 MB
  unsigned short* wqb   = (unsigned short*)p; p += 32*256*2;
  unsigned short* wkb   = (unsigned short*)p; p += 32*256*2;
  unsigned short* wvb   = (unsigned short*)p; p += 256*256*2;
  float* biasq          = (float*)p;          p += 32*4;
  float* biask          = (float*)p;          p += 32*4;
  float* biasv          = (float*)p;          p += 256*4;
  unsigned short* parti = (unsigned short*)p; p += (size_t)512*16384*2;     // 16 MB
  float* statsg         = (float*)p;          p += (size_t)512*64*2*4;      // 256 KB

  fold_w_kernel<<<256, 256, 0, stream>>>(wq,wk,wv,gq,bq,mq,vq,gk,bk,mk,vk,gv,bv,mv,vv,
                                         wqb,wkb,wvb,biasq,biask,biasv);
  pre_kernel<<<dim3(64,4,3), 256, 0, stream>>>(x1, x2, wqb, wkb, wvb,
                                               biasq, biask, biasv, x1u, Qb, Kb, Vb);
  attn_kernel<<<dim3(64,4,2), 512, 0, stream>>>(Qb, Kb, Vb, parti, statsg);
  combine_kernel<<<dim3(4,64,4), 256, 0, stream>>>(parti, statsg, x1u, gamma, out);
}